// Round 5
// baseline (553.812 us; speedup 1.0000x reference)
//
#include <hip/hip_runtime.h>

typedef unsigned short u16;
typedef u16 u16x4 __attribute__((ext_vector_type(4)));
typedef short short8 __attribute__((ext_vector_type(8)));
typedef float f32x4 __attribute__((ext_vector_type(4)));

__device__ __forceinline__ float elu_f(float x) { return x > 0.f ? x : expm1f(x); }
__device__ __forceinline__ float lrelu_f(float x) { return x > 0.f ? x : 0.2f * x; }

__device__ __forceinline__ u16 f2b(float f) {
  union { float f; unsigned u; } v; v.f = f;
  unsigned r = v.u + 0x7FFF + ((v.u >> 16) & 1);
  return (u16)(r >> 16);
}
__device__ __forceinline__ float b2f(u16 u) {
  union { unsigned u; float f; } v; v.u = ((unsigned)u) << 16; return v.f;
}
__device__ __forceinline__ float blo(unsigned v) {
  union { unsigned u; float f; } x; x.u = v << 16; return x.f;
}
__device__ __forceinline__ float bhi(unsigned v) {
  union { unsigned u; float f; } x; x.u = v & 0xffff0000u; return x.f;
}

// ---------------- CSR build ----------------
__global__ void deg_count_k(const int* __restrict__ src, const int* __restrict__ dst,
                            int E, int n, int* __restrict__ deg) {
  int e = blockIdx.x * blockDim.x + threadIdx.x;
  if (e < E) {
    atomicAdd(&deg[dst[e]], 1);
  } else if (e < E + n) {
    atomicAdd(&deg[e - E], 1);  // self loop
  }
}

__global__ __launch_bounds__(256) void block_sum_k(const int* __restrict__ deg,
                                                   int* __restrict__ bsum, int n) {
  int i = blockIdx.x * 256 + threadIdx.x;
  int v = (i < n) ? deg[i] : 0;
#pragma unroll
  for (int off = 1; off < 64; off <<= 1) v += __shfl_xor(v, off);
  __shared__ int ws[4];
  if ((threadIdx.x & 63) == 0) ws[threadIdx.x >> 6] = v;
  __syncthreads();
  if (threadIdx.x == 0) bsum[blockIdx.x] = ws[0] + ws[1] + ws[2] + ws[3];
}

__global__ void scan_bsum_k(int* __restrict__ bsum, int nb) {
  __shared__ int s[1024];
  int tid = threadIdx.x;
  int v = (tid < nb) ? bsum[tid] : 0;
  s[tid] = v;
  __syncthreads();
  for (int off = 1; off < 1024; off <<= 1) {
    int t = (tid >= off) ? s[tid - off] : 0;
    __syncthreads();
    s[tid] += t;
    __syncthreads();
  }
  if (tid < nb) bsum[tid] = s[tid] - v;  // exclusive
}

__global__ __launch_bounds__(256) void block_scan_k(const int* __restrict__ deg,
                                                    const int* __restrict__ bsum,
                                                    int* __restrict__ rowptr,
                                                    int* __restrict__ cursor, int n) {
  int i = blockIdx.x * 256 + threadIdx.x;
  int lane = threadIdx.x & 63, w = threadIdx.x >> 6;
  int v = (i < n) ? deg[i] : 0;
  int x = v;
#pragma unroll
  for (int off = 1; off < 64; off <<= 1) {
    int t = __shfl_up(x, off);
    if (lane >= off) x += t;
  }
  __shared__ int ws[4];
  if (lane == 63) ws[w] = x;
  __syncthreads();
  int add = bsum[blockIdx.x];
  for (int j = 0; j < w; ++j) add += ws[j];
  int excl = x - v + add;
  if (i < n) {
    cursor[i] = excl;
    rowptr[i + 1] = excl + v;
  }
  if (i == 0) rowptr[0] = 0;
}

__global__ void scatter_k(const int* __restrict__ src, const int* __restrict__ dst,
                          int E, int n, int* __restrict__ cursor, int* __restrict__ col) {
  int e = blockIdx.x * blockDim.x + threadIdx.x;
  if (e < E) {
    int d = dst[e];
    int pos = atomicAdd(&cursor[d], 1);
    col[pos] = src[e];
  } else if (e < E + n) {
    int d = e - E;
    int pos = atomicAdd(&cursor[d], 1);
    col[pos] = d;  // self loop
  }
}

// all 4 weight matrices -> bf16 in one dispatch
__global__ __launch_bounds__(256) void cvt_weights_k(const float* __restrict__ pw,
                                                     const float* __restrict__ w0,
                                                     const float* __restrict__ w1,
                                                     const float* __restrict__ w2,
                                                     u16* __restrict__ dp, u16* __restrict__ d0,
                                                     u16* __restrict__ d1, u16* __restrict__ d2) {
  int i = blockIdx.x * 256 + threadIdx.x;
  if (i < 8192) dp[i] = f2b(pw[i]);
  else if (i < 8192 + 16384) d0[i - 8192] = f2b(w0[i - 8192]);
  else if (i < 8192 + 16384 + 65536) d1[i - 24576] = f2b(w1[i - 24576]);
  else if (i < 8192 + 16384 + 131072) d2[i - 90112] = f2b(w2[i - 90112]);
}

// vectorized f32 -> bf16, sz multiple of 8
__global__ void cvt8_k(const float* __restrict__ in, u16* __restrict__ o, int sz) {
  int i = (blockIdx.x * blockDim.x + threadIdx.x) * 8;
  if (i >= sz) return;
  float4 a = *reinterpret_cast<const float4*>(&in[i]);
  float4 b = *reinterpret_cast<const float4*>(&in[i + 4]);
  u16x4 o0, o1;
  o0.x = f2b(a.x); o0.y = f2b(a.y); o0.z = f2b(a.z); o0.w = f2b(a.w);
  o1.x = f2b(b.x); o1.y = f2b(b.y); o1.z = f2b(b.z); o1.w = f2b(b.w);
  *reinterpret_cast<u16x4*>(&o[i]) = o0;
  *reinterpret_cast<u16x4*>(&o[i + 4]) = o1;
}

// ---------------- bf16 MFMA GEMM: Cb[n,ncols](bf16,ldc) = A[n,K](bf16,lda) @ W[ncols,K]^T ----------------
template <int BIASELU>
__global__ __launch_bounds__(256) void gemm_bf16_k(const u16* __restrict__ A, int lda,
                                                   const u16* __restrict__ W,
                                                   const float* __restrict__ bias,
                                                   u16* __restrict__ Cb, int ldc,
                                                   int n, int K, int ncols) {
  __shared__ int4 Abuf[1024];  // 128 rows x 128B, XOR-swizzled
  __shared__ int4 Bbuf[1024];
  char* Asb = (char*)Abuf;
  char* Bsb = (char*)Bbuf;
  const int t = threadIdx.x;
  const int lane = t & 63, w = t >> 6;
  const int wrow = w >> 1, wcol = w & 1;
  const int row0 = blockIdx.x * 128, col0 = blockIdx.y * 128;
  f32x4 acc[4][4];
#pragma unroll
  for (int m = 0; m < 4; ++m)
#pragma unroll
    for (int nf = 0; nf < 4; ++nf) acc[m][nf] = (f32x4){0.f, 0.f, 0.f, 0.f};

  for (int k0 = 0; k0 < K; k0 += 64) {
#pragma unroll
    for (int i = 0; i < 4; ++i) {
      int ci = i * 256 + t;           // 16B chunk index, 0..1023
      int r = ci >> 3;                // row 0..127
      int b = (ci & 7) << 4;          // byte-in-row
      int sw = b ^ ((r & 7) << 4);
      int ar = row0 + r; ar = ar < n ? ar : n - 1;
      int4 av = *reinterpret_cast<const int4*>(&A[(size_t)ar * lda + k0 + (b >> 1)]);
      *reinterpret_cast<int4*>(Asb + r * 128 + sw) = av;
      int wr = col0 + r; wr = wr < ncols ? wr : ncols - 1;
      int4 wv = *reinterpret_cast<const int4*>(&W[(size_t)wr * K + k0 + (b >> 1)]);
      *reinterpret_cast<int4*>(Bsb + r * 128 + sw) = wv;
    }
    __syncthreads();
#pragma unroll
    for (int ks = 0; ks < 2; ++ks) {
      short8 af[4], bf[4];
      int kb = ks * 64 + ((lane >> 4) << 4);
#pragma unroll
      for (int m = 0; m < 4; ++m) {
        int r = wrow * 64 + m * 16 + (lane & 15);
        af[m] = *reinterpret_cast<const short8*>(Asb + r * 128 + (kb ^ ((r & 7) << 4)));
      }
#pragma unroll
      for (int nf = 0; nf < 4; ++nf) {
        int r = wcol * 64 + nf * 16 + (lane & 15);
        bf[nf] = *reinterpret_cast<const short8*>(Bsb + r * 128 + (kb ^ ((r & 7) << 4)));
      }
#pragma unroll
      for (int m = 0; m < 4; ++m)
#pragma unroll
        for (int nf = 0; nf < 4; ++nf)
          acc[m][nf] = __builtin_amdgcn_mfma_f32_16x16x32_bf16(af[m], bf[nf], acc[m][nf], 0, 0, 0);
    }
    __syncthreads();
  }
  // epilogue: C/D layout col=lane&15, row=(lane>>4)*4+j
#pragma unroll
  for (int m = 0; m < 4; ++m) {
#pragma unroll
    for (int j = 0; j < 4; ++j) {
      int rg = row0 + wrow * 64 + m * 16 + (lane >> 4) * 4 + j;
      if (rg >= n) continue;
#pragma unroll
      for (int nf = 0; nf < 4; ++nf) {
        int cg = col0 + wcol * 64 + nf * 16 + (lane & 15);
        if (cg >= ncols) continue;
        float v = acc[m][nf][j];
        if (BIASELU) v = elu_f(v + bias[cg]);
        Cb[(size_t)rg * ldc + cg] = f2b(v);
      }
    }
  }
}

// ---------------- attention scores from bf16 feat ----------------
__global__ __launch_bounds__(256) void attn_scores_k(const u16* __restrict__ feat,
                                                     const float* __restrict__ a_s,
                                                     const float* __restrict__ a_d,
                                                     float* __restrict__ asrcN,
                                                     float* __restrict__ adstN, int n) {
  int wave = threadIdx.x >> 6, lane = threadIdx.x & 63;
  int node = blockIdx.x * 4 + wave;
  if (node >= n) return;
  u16x4 f = *reinterpret_cast<const u16x4*>(&feat[(size_t)node * 256 + lane * 4]);
  float4 as = *reinterpret_cast<const float4*>(&a_s[lane * 4]);
  float4 ad = *reinterpret_cast<const float4*>(&a_d[lane * 4]);
  float fx = b2f(f.x), fy = b2f(f.y), fz = b2f(f.z), fw = b2f(f.w);
  float ps = fx * as.x + fy * as.y + fz * as.z + fw * as.w;
  float pd = fx * ad.x + fy * ad.y + fz * ad.z + fw * ad.w;
#pragma unroll
  for (int off = 1; off < 16; off <<= 1) {
    ps += __shfl_xor(ps, off);
    pd += __shfl_xor(pd, off);
  }
  if ((lane & 15) == 0) {
    int h = lane >> 4;
    asrcN[(size_t)node * 4 + h] = ps;
    adstN[(size_t)node * 4 + h] = pd;
  }
}

// ---------------- normalized softmax coefficients, thread per node ----------------
__global__ __launch_bounds__(256) void coef_k(const int* __restrict__ col,
                                              const int* __restrict__ rowptr,
                                              const float* __restrict__ asrcN,
                                              const float* __restrict__ adstN,
                                              float* __restrict__ coef, int n) {
  int node = blockIdx.x * 256 + threadIdx.x;
  if (node >= n) return;
  float4 ad = *reinterpret_cast<const float4*>(&adstN[(size_t)node * 4]);
  int s0 = rowptr[node], s1 = rowptr[node + 1];
  float dx = 0.f, dy = 0.f, dz = 0.f, dw = 0.f;
  for (int e = s0; e < s1; ++e) {
    int s = col[e];
    float4 as = *reinterpret_cast<const float4*>(&asrcN[(size_t)s * 4]);
    float4 v;
    v.x = __expf(lrelu_f(as.x + ad.x));  // shift-invariant softmax; |a| <~ 5
    v.y = __expf(lrelu_f(as.y + ad.y));
    v.z = __expf(lrelu_f(as.z + ad.z));
    v.w = __expf(lrelu_f(as.w + ad.w));
    *reinterpret_cast<float4*>(&coef[(size_t)e * 4]) = v;
    dx += v.x; dy += v.y; dz += v.z; dw += v.w;
  }
  float ix = 1.f / dx, iy = 1.f / dy, iz = 1.f / dz, iw = 1.f / dw;
  for (int e = s0; e < s1; ++e) {
    float4 v = *reinterpret_cast<const float4*>(&coef[(size_t)e * 4]);
    v.x *= ix; v.y *= iy; v.z *= iz; v.w *= iw;
    *reinterpret_cast<float4*>(&coef[(size_t)e * 4]) = v;
  }
}

// ---------------- fused GAT aggregation + bias + LayerNorm + ELU ----------------
// wave = 1 node, two 32-lane halves each stream half the edges; lane holds 8 cols (16B loads)
// MODE 0: LN(256) -> bf16 row at (u16*)out + node*256
// MODE 1: head-mean -> bias -> LN(64) -> ELU -> f32 out[node*64..]
template <int MODE>
__global__ __launch_bounds__(256) void gat_agg3_k(const u16* __restrict__ feat,
                                                  const float* __restrict__ coef,
                                                  const int* __restrict__ rowptr,
                                                  const int* __restrict__ col,
                                                  const float* __restrict__ bias,
                                                  const float* __restrict__ g,
                                                  const float* __restrict__ be,
                                                  void* __restrict__ out, int n) {
  int wave = threadIdx.x >> 6, lane = threadIdx.x & 63;
  int node = blockIdx.x * 4 + wave;
  if (node >= n) return;
  int half = lane >> 5, sl = lane & 31;
  int h = sl >> 3;                       // head of this lane's 8 cols
  const u16* fbase = feat + sl * 8;      // col offset within row
  int s0 = rowptr[node], s1 = rowptr[node + 1];
  float a[8] = {};
  int e = s0 + half;
  for (; e + 2 < s1; e += 4) {
    int sa = col[e], sb = col[e + 2];
    float ca = coef[(size_t)e * 4 + h];
    float cb = coef[(size_t)(e + 2) * 4 + h];
    int4 fa = *reinterpret_cast<const int4*>(fbase + (size_t)sa * 256);
    int4 fb = *reinterpret_cast<const int4*>(fbase + (size_t)sb * 256);
    a[0] += ca * blo(fa.x); a[1] += ca * bhi(fa.x);
    a[2] += ca * blo(fa.y); a[3] += ca * bhi(fa.y);
    a[4] += ca * blo(fa.z); a[5] += ca * bhi(fa.z);
    a[6] += ca * blo(fa.w); a[7] += ca * bhi(fa.w);
    a[0] += cb * blo(fb.x); a[1] += cb * bhi(fb.x);
    a[2] += cb * blo(fb.y); a[3] += cb * bhi(fb.y);
    a[4] += cb * blo(fb.z); a[5] += cb * bhi(fb.z);
    a[6] += cb * blo(fb.w); a[7] += cb * bhi(fb.w);
  }
  if (e < s1) {
    int s = col[e];
    float c = coef[(size_t)e * 4 + h];
    int4 f = *reinterpret_cast<const int4*>(fbase + (size_t)s * 256);
    a[0] += c * blo(f.x); a[1] += c * bhi(f.x);
    a[2] += c * blo(f.y); a[3] += c * bhi(f.y);
    a[4] += c * blo(f.z); a[5] += c * bhi(f.z);
    a[6] += c * blo(f.w); a[7] += c * bhi(f.w);
  }
  // combine the two edge-stream halves (both halves then hold full sums)
#pragma unroll
  for (int k = 0; k < 8; ++k) a[k] += __shfl_xor(a[k], 32);

  if (MODE == 0) {
    float4 b0 = *reinterpret_cast<const float4*>(&bias[sl * 8]);
    float4 b1 = *reinterpret_cast<const float4*>(&bias[sl * 8 + 4]);
    a[0] += b0.x; a[1] += b0.y; a[2] += b0.z; a[3] += b0.w;
    a[4] += b1.x; a[5] += b1.y; a[6] += b1.z; a[7] += b1.w;
    float s = 0.f;
#pragma unroll
    for (int k = 0; k < 8; ++k) s += a[k];
#pragma unroll
    for (int off = 1; off < 64; off <<= 1) s += __shfl_xor(s, off);
    float mu = s * (1.f / 512.f);  // each col counted twice (both halves)
    float q = 0.f;
#pragma unroll
    for (int k = 0; k < 8; ++k) { a[k] -= mu; q += a[k] * a[k]; }
#pragma unroll
    for (int off = 1; off < 64; off <<= 1) q += __shfl_xor(q, off);
    float inv2 = rsqrtf(q * (1.f / 512.f) + 1e-5f);
    float4 g0 = *reinterpret_cast<const float4*>(&g[sl * 8]);
    float4 g1 = *reinterpret_cast<const float4*>(&g[sl * 8 + 4]);
    float4 e0 = *reinterpret_cast<const float4*>(&be[sl * 8]);
    float4 e1 = *reinterpret_cast<const float4*>(&be[sl * 8 + 4]);
    if (half == 0) {
      int4 o;
      o.x = ((unsigned)f2b(elu_f(a[1] * inv2 * g0.y + e0.y)) << 16) | f2b(elu_f(a[0] * inv2 * g0.x + e0.x));
      o.y = ((unsigned)f2b(elu_f(a[3] * inv2 * g0.w + e0.w)) << 16) | f2b(elu_f(a[2] * inv2 * g0.z + e0.z));
      o.z = ((unsigned)f2b(elu_f(a[5] * inv2 * g1.y + e1.y)) << 16) | f2b(elu_f(a[4] * inv2 * g1.x + e1.x));
      o.w = ((unsigned)f2b(elu_f(a[7] * inv2 * g1.w + e1.w)) << 16) | f2b(elu_f(a[6] * inv2 * g1.z + e1.z));
      *reinterpret_cast<int4*>((u16*)out + (size_t)node * 256 + sl * 8) = o;
    }
  } else {
    // mean over heads: cols (sl&7)*8+k live on lanes sl, sl+8, sl+16, sl+24 (and both halves)
#pragma unroll
    for (int k = 0; k < 8; ++k) {
      a[k] += __shfl_xor(a[k], 8);
      a[k] += __shfl_xor(a[k], 16);
    }
    int qd = sl & 7;  // col group (qd*8 .. qd*8+7)
    float4 b0 = *reinterpret_cast<const float4*>(&bias[qd * 8]);
    float4 b1 = *reinterpret_cast<const float4*>(&bias[qd * 8 + 4]);
    a[0] = 0.25f * a[0] + b0.x; a[1] = 0.25f * a[1] + b0.y;
    a[2] = 0.25f * a[2] + b0.z; a[3] = 0.25f * a[3] + b0.w;
    a[4] = 0.25f * a[4] + b1.x; a[5] = 0.25f * a[5] + b1.y;
    a[6] = 0.25f * a[6] + b1.z; a[7] = 0.25f * a[7] + b1.w;
    float s = 0.f;
#pragma unroll
    for (int k = 0; k < 8; ++k) s += a[k];
#pragma unroll
    for (int off = 1; off < 8; off <<= 1) s += __shfl_xor(s, off);  // lanes 0..7 cover all 64 cols
    float mu = s * (1.f / 64.f);
    float q = 0.f;
#pragma unroll
    for (int k = 0; k < 8; ++k) { a[k] -= mu; q += a[k] * a[k]; }
#pragma unroll
    for (int off = 1; off < 8; off <<= 1) q += __shfl_xor(q, off);
    float inv2 = rsqrtf(q * (1.f / 64.f) + 1e-5f);
    if (half == 0 && sl < 8) {
      float4 g0 = *reinterpret_cast<const float4*>(&g[qd * 8]);
      float4 g1 = *reinterpret_cast<const float4*>(&g[qd * 8 + 4]);
      float4 e0 = *reinterpret_cast<const float4*>(&be[qd * 8]);
      float4 e1 = *reinterpret_cast<const float4*>(&be[qd * 8 + 4]);
      float4 o0, o1;
      o0.x = elu_f(a[0] * inv2 * g0.x + e0.x);
      o0.y = elu_f(a[1] * inv2 * g0.y + e0.y);
      o0.z = elu_f(a[2] * inv2 * g0.z + e0.z);
      o0.w = elu_f(a[3] * inv2 * g0.w + e0.w);
      o1.x = elu_f(a[4] * inv2 * g1.x + e1.x);
      o1.y = elu_f(a[5] * inv2 * g1.y + e1.y);
      o1.z = elu_f(a[6] * inv2 * g1.z + e1.z);
      o1.w = elu_f(a[7] * inv2 * g1.w + e1.w);
      float* op = (float*)out + (size_t)node * 64 + qd * 8;
      *reinterpret_cast<float4*>(op) = o0;
      *reinterpret_cast<float4*>(op + 4) = o1;
    }
  }
}

// ---------------- value head: out[n,4] ----------------
__global__ __launch_bounds__(256) void value_head_k(const float* __restrict__ hh,
                                                    const float* __restrict__ vw1,
                                                    const float* __restrict__ vb1,
                                                    const float* __restrict__ vw2,
                                                    const float* __restrict__ vb2,
                                                    float* __restrict__ out, int n) {
  __shared__ float w1s[32 * 65];
  __shared__ float hs[4][64];
  __shared__ float vs[4][33];
  int tid = threadIdx.x;
  for (int i = tid; i < 2048; i += 256) w1s[(i >> 6) * 65 + (i & 63)] = vw1[i];
  int wave = tid >> 6, lane = tid & 63;
  int node = blockIdx.x * 4 + wave;
  int nc = node < n ? node : n - 1;
  hs[wave][lane] = hh[(size_t)nc * 64 + lane];
  __syncthreads();
  int j = lane & 31, half = lane >> 5;
  float p = 0.f;
#pragma unroll
  for (int c = 0; c < 32; ++c) p += hs[wave][half * 32 + c] * w1s[j * 65 + half * 32 + c];
  p += __shfl_xor(p, 32);
  float v = elu_f(p + vb1[j]);
  if (half == 0) vs[wave][j] = v;
  __syncthreads();
  if (lane < 4 && node < n) {
    float o = vb2[lane];
#pragma unroll
    for (int jj = 0; jj < 32; ++jj) o += vs[wave][jj] * vw2[lane * 32 + jj];
    out[(size_t)node * 4 + lane] = o;
  }
}

extern "C" void kernel_launch(void* const* d_in, const int* in_sizes, int n_in,
                              void* d_out, int out_size, void* d_ws, size_t ws_size,
                              hipStream_t stream) {
  const float* x      = (const float*)d_in[0];
  const int*   esrc   = (const int*)d_in[1];
  const int*   edst   = (const int*)d_in[2];
  const float* proj_w = (const float*)d_in[3];
  const float* proj_b = (const float*)d_in[4];
  const float* w[3]   = {(const float*)d_in[5],  (const float*)d_in[11], (const float*)d_in[17]};
  const float* a_s[3] = {(const float*)d_in[6],  (const float*)d_in[12], (const float*)d_in[18]};
  const float* a_d[3] = {(const float*)d_in[7],  (const float*)d_in[13], (const float*)d_in[19]};
  const float* bb[3]  = {(const float*)d_in[8],  (const float*)d_in[14], (const float*)d_in[20]};
  const float* gg[3]  = {(const float*)d_in[9],  (const float*)d_in[15], (const float*)d_in[21]};
  const float* be[3]  = {(const float*)d_in[10], (const float*)d_in[16], (const float*)d_in[22]};
  const float* vw1 = (const float*)d_in[23];
  const float* vb1 = (const float*)d_in[24];
  const float* vw2 = (const float*)d_in[25];
  const float* vb2 = (const float*)d_in[26];
  float* outp = (float*)d_out;

  const int n = in_sizes[0] / 128;
  const int E = in_sizes[1];
  const int EE = E + n;
  const int nbl = (n + 255) / 256;  // scan blocks (<=1024 supported)

  // ---- workspace layout ----
  char* p = (char*)d_ws;
  auto alloc = [&](size_t bytes) { char* r = p; p += (bytes + 255) & ~(size_t)255; return r; };
  u16*   hA    = (u16*)alloc((size_t)n * 512);     // packed bf16 [n,256] layer input; hfinal f32 [n,64] later
  u16*   featB = (u16*)alloc((size_t)n * 512);     // bf16 [n,256] gemm output; x bf16 first
  float* coef  = (float*)alloc((size_t)EE * 16);   // normalized softmax coefs [EE,4]
  float* asrcN = (float*)alloc((size_t)n * 16);
  float* adstN = (float*)alloc((size_t)n * 16);
  u16* wbp = (u16*)alloc(64 * 128 * 2);
  u16* wb[3];
  wb[0] = (u16*)alloc(256 * 64 * 2);
  wb[1] = (u16*)alloc(256 * 256 * 2);
  wb[2] = (u16*)alloc(256 * 256 * 2);
  int* deg    = (int*)alloc((size_t)n * 4);
  int* rowptr = (int*)alloc((size_t)(n + 1) * 4);
  int* cursor = (int*)alloc((size_t)n * 4);
  int* col    = (int*)alloc((size_t)EE * 4);
  int* bsum   = (int*)alloc((size_t)nbl * 4);
  float* hfinal = (float*)hA;  // f32 [n,64]; hA dead after layer-2 gemm

  // ---- CSR build ----
  hipMemsetAsync(deg, 0, (size_t)n * sizeof(int), stream);
  deg_count_k<<<(EE + 255) / 256, 256, 0, stream>>>(esrc, edst, E, n, deg);
  block_sum_k<<<nbl, 256, 0, stream>>>(deg, bsum, n);
  scan_bsum_k<<<1, 1024, 0, stream>>>(bsum, nbl);
  block_scan_k<<<nbl, 256, 0, stream>>>(deg, bsum, rowptr, cursor, n);
  scatter_k<<<(EE + 255) / 256, 256, 0, stream>>>(esrc, edst, E, n, cursor, col);

  // ---- dtype conversions ----
  cvt8_k<<<((size_t)n * 128 / 8 + 255) / 256, 256, 0, stream>>>(x, featB, n * 128);
  cvt_weights_k<<<(221184 + 255) / 256, 256, 0, stream>>>(proj_w, w[0], w[1], w[2],
                                                          wbp, wb[0], wb[1], wb[2]);

  const int nb4 = (n + 3) / 4;
  const int nbg = (n + 127) / 128;
  const int nbn = (n + 255) / 256;
  dim3 blk(256);

  // ---- projection: hA[n,0..63] = elu(x @ proj_w^T + proj_b), bf16, ldc=256 ----
  gemm_bf16_k<1><<<dim3(nbg, 1), blk, 0, stream>>>(featB, 128, wbp, proj_b, hA, 256, n, 128, 64);

  const int Kin[3] = {64, 256, 256};
  for (int i = 0; i < 3; ++i) {
    gemm_bf16_k<0><<<dim3(nbg, 2), blk, 0, stream>>>(hA, 256, wb[i], nullptr, featB, 256, n, Kin[i], 256);
    attn_scores_k<<<nb4, blk, 0, stream>>>(featB, a_s[i], a_d[i], asrcN, adstN, n);
    coef_k<<<nbn, blk, 0, stream>>>(col, rowptr, asrcN, adstN, coef, n);
    if (i < 2) {
      gat_agg3_k<0><<<nb4, blk, 0, stream>>>(featB, coef, rowptr, col, bb[i], gg[i], be[i], (void*)hA, n);
    } else {
      gat_agg3_k<1><<<nb4, blk, 0, stream>>>(featB, coef, rowptr, col, bb[i], gg[i], be[i], (void*)hfinal, n);
    }
  }

  // ---- value head ----
  value_head_k<<<nb4, blk, 0, stream>>>(hfinal, vw1, vb1, vw2, vb2, outp, n);
}

// Round 6
// 462.706 us; speedup vs baseline: 1.1969x; 1.1969x over previous
//
#include <hip/hip_runtime.h>

typedef unsigned short u16;
typedef u16 u16x4 __attribute__((ext_vector_type(4)));
typedef short short8 __attribute__((ext_vector_type(8)));
typedef float f32x4 __attribute__((ext_vector_type(4)));

__device__ __forceinline__ float elu_f(float x) { return x > 0.f ? x : expm1f(x); }
__device__ __forceinline__ float lrelu_f(float x) { return x > 0.f ? x : 0.2f * x; }

__device__ __forceinline__ u16 f2b(float f) {
  union { float f; unsigned u; } v; v.f = f;
  unsigned r = v.u + 0x7FFF + ((v.u >> 16) & 1);
  return (u16)(r >> 16);
}
__device__ __forceinline__ float b2f(u16 u) {
  union { unsigned u; float f; } v; v.u = ((unsigned)u) << 16; return v.f;
}

// ---------------- CSR build ----------------
__global__ void deg_count_k(const int* __restrict__ src, const int* __restrict__ dst,
                            int E, int n, int* __restrict__ deg) {
  int e = blockIdx.x * blockDim.x + threadIdx.x;
  if (e < E) {
    atomicAdd(&deg[dst[e]], 1);
  } else if (e < E + n) {
    atomicAdd(&deg[e - E], 1);  // self loop
  }
}

__global__ __launch_bounds__(256) void block_sum_k(const int* __restrict__ deg,
                                                   int* __restrict__ bsum, int n) {
  int i = blockIdx.x * 256 + threadIdx.x;
  int v = (i < n) ? deg[i] : 0;
#pragma unroll
  for (int off = 1; off < 64; off <<= 1) v += __shfl_xor(v, off);
  __shared__ int ws[4];
  if ((threadIdx.x & 63) == 0) ws[threadIdx.x >> 6] = v;
  __syncthreads();
  if (threadIdx.x == 0) bsum[blockIdx.x] = ws[0] + ws[1] + ws[2] + ws[3];
}

__global__ void scan_bsum_k(int* __restrict__ bsum, int nb) {
  __shared__ int s[1024];
  int tid = threadIdx.x;
  int v = (tid < nb) ? bsum[tid] : 0;
  s[tid] = v;
  __syncthreads();
  for (int off = 1; off < 1024; off <<= 1) {
    int t = (tid >= off) ? s[tid - off] : 0;
    __syncthreads();
    s[tid] += t;
    __syncthreads();
  }
  if (tid < nb) bsum[tid] = s[tid] - v;  // exclusive
}

__global__ __launch_bounds__(256) void block_scan_k(const int* __restrict__ deg,
                                                    const int* __restrict__ bsum,
                                                    int* __restrict__ rowptr,
                                                    int* __restrict__ cursor, int n) {
  int i = blockIdx.x * 256 + threadIdx.x;
  int lane = threadIdx.x & 63, w = threadIdx.x >> 6;
  int v = (i < n) ? deg[i] : 0;
  int x = v;
#pragma unroll
  for (int off = 1; off < 64; off <<= 1) {
    int t = __shfl_up(x, off);
    if (lane >= off) x += t;
  }
  __shared__ int ws[4];
  if (lane == 63) ws[w] = x;
  __syncthreads();
  int add = bsum[blockIdx.x];
  for (int j = 0; j < w; ++j) add += ws[j];
  int excl = x - v + add;
  if (i < n) {
    cursor[i] = excl;
    rowptr[i + 1] = excl + v;
  }
  if (i == 0) rowptr[0] = 0;
}

__global__ void scatter_k(const int* __restrict__ src, const int* __restrict__ dst,
                          int E, int n, int* __restrict__ cursor,
                          int* __restrict__ col, int* __restrict__ dst2) {
  int e = blockIdx.x * blockDim.x + threadIdx.x;
  if (e < E) {
    int d = dst[e];
    int pos = atomicAdd(&cursor[d], 1);
    col[pos] = src[e];
    dst2[pos] = d;
  } else if (e < E + n) {
    int d = e - E;
    int pos = atomicAdd(&cursor[d], 1);
    col[pos] = d;  // self loop
    dst2[pos] = d;
  }
}

// ---------------- all conversions (x vectorized + 4 weight mats) in ONE dispatch ----------------
__global__ __launch_bounds__(256) void cvt_all_k(const float* __restrict__ x, u16* __restrict__ xb,
                                                 int nx8,
                                                 const float* __restrict__ pw,
                                                 const float* __restrict__ w0,
                                                 const float* __restrict__ w1,
                                                 const float* __restrict__ w2,
                                                 u16* __restrict__ dp, u16* __restrict__ d0,
                                                 u16* __restrict__ d1, u16* __restrict__ d2) {
  int i = blockIdx.x * 256 + threadIdx.x;
  if (i < nx8) {
    int j = i * 8;
    float4 a = *reinterpret_cast<const float4*>(&x[j]);
    float4 b = *reinterpret_cast<const float4*>(&x[j + 4]);
    u16x4 o0, o1;
    o0.x = f2b(a.x); o0.y = f2b(a.y); o0.z = f2b(a.z); o0.w = f2b(a.w);
    o1.x = f2b(b.x); o1.y = f2b(b.y); o1.z = f2b(b.z); o1.w = f2b(b.w);
    *reinterpret_cast<u16x4*>(&xb[j]) = o0;
    *reinterpret_cast<u16x4*>(&xb[j + 4]) = o1;
  } else {
    int j = i - nx8;
    if (j < 8192) dp[j] = f2b(pw[j]);
    else if (j < 24576) d0[j - 8192] = f2b(w0[j - 8192]);
    else if (j < 90112) d1[j - 24576] = f2b(w1[j - 24576]);
    else if (j < 155648) d2[j - 90112] = f2b(w2[j - 90112]);
  }
}

// ---------------- bf16 MFMA GEMM (+ optional fused attention scores) ----------------
// Cb[n,ncols](bf16,ldc) = A[n,K](bf16,lda) @ W[ncols,K]^T
// ATTN=1 (requires ncols=256, grid.y=2): also writes asrcN/adstN[n,4] for head = 2*by + wcol
template <int BIASELU, int ATTN>
__global__ __launch_bounds__(256) void gemm_bf16_k(const u16* __restrict__ A, int lda,
                                                   const u16* __restrict__ W,
                                                   const float* __restrict__ bias,
                                                   u16* __restrict__ Cb, int ldc,
                                                   int n, int K, int ncols,
                                                   const float* __restrict__ a_sv,
                                                   const float* __restrict__ a_dv,
                                                   float* __restrict__ asrcN,
                                                   float* __restrict__ adstN) {
  __shared__ int4 Abuf[1024];  // 128 rows x 128B, XOR-swizzled
  __shared__ int4 Bbuf[1024];
  char* Asb = (char*)Abuf;
  char* Bsb = (char*)Bbuf;
  const int t = threadIdx.x;
  const int lane = t & 63, w = t >> 6;
  const int wrow = w >> 1, wcol = w & 1;
  const int row0 = blockIdx.x * 128, col0 = blockIdx.y * 128;
  f32x4 acc[4][4];
#pragma unroll
  for (int m = 0; m < 4; ++m)
#pragma unroll
    for (int nf = 0; nf < 4; ++nf) acc[m][nf] = (f32x4){0.f, 0.f, 0.f, 0.f};

  for (int k0 = 0; k0 < K; k0 += 64) {
#pragma unroll
    for (int i = 0; i < 4; ++i) {
      int ci = i * 256 + t;           // 16B chunk index, 0..1023
      int r = ci >> 3;                // row 0..127
      int b = (ci & 7) << 4;          // byte-in-row
      int sw = b ^ ((r & 7) << 4);
      int ar = row0 + r; ar = ar < n ? ar : n - 1;
      int4 av = *reinterpret_cast<const int4*>(&A[(size_t)ar * lda + k0 + (b >> 1)]);
      *reinterpret_cast<int4*>(Asb + r * 128 + sw) = av;
      int wr = col0 + r; wr = wr < ncols ? wr : ncols - 1;
      int4 wv = *reinterpret_cast<const int4*>(&W[(size_t)wr * K + k0 + (b >> 1)]);
      *reinterpret_cast<int4*>(Bsb + r * 128 + sw) = wv;
    }
    __syncthreads();
#pragma unroll
    for (int ks = 0; ks < 2; ++ks) {
      short8 af[4], bf[4];
      int kb = ks * 64 + ((lane >> 4) << 4);
#pragma unroll
      for (int m = 0; m < 4; ++m) {
        int r = wrow * 64 + m * 16 + (lane & 15);
        af[m] = *reinterpret_cast<const short8*>(Asb + r * 128 + (kb ^ ((r & 7) << 4)));
      }
#pragma unroll
      for (int nf = 0; nf < 4; ++nf) {
        int r = wcol * 64 + nf * 16 + (lane & 15);
        bf[nf] = *reinterpret_cast<const short8*>(Bsb + r * 128 + (kb ^ ((r & 7) << 4)));
      }
#pragma unroll
      for (int m = 0; m < 4; ++m)
#pragma unroll
        for (int nf = 0; nf < 4; ++nf)
          acc[m][nf] = __builtin_amdgcn_mfma_f32_16x16x32_bf16(af[m], bf[nf], acc[m][nf], 0, 0, 0);
    }
    __syncthreads();
  }
  // epilogue: C/D layout col=lane&15, row=(lane>>4)*4+j
#pragma unroll
  for (int m = 0; m < 4; ++m) {
#pragma unroll
    for (int j = 0; j < 4; ++j) {
      int rg = row0 + wrow * 64 + m * 16 + (lane >> 4) * 4 + j;
      if (rg >= n) continue;
#pragma unroll
      for (int nf = 0; nf < 4; ++nf) {
        int cg = col0 + wcol * 64 + nf * 16 + (lane & 15);
        if (cg >= ncols) continue;
        float v = acc[m][nf][j];
        if (BIASELU) v = elu_f(v + bias[cg]);
        Cb[(size_t)rg * ldc + cg] = f2b(v);
      }
    }
  }
  if (ATTN) {
    // this wave's 64-col half = exactly one head: head = 2*by + wcol
    int h = (col0 >> 6) + wcol;
    int ch = lane & 15;
    float as_c[4], ad_c[4];
#pragma unroll
    for (int nf = 0; nf < 4; ++nf) {
      as_c[nf] = a_sv[h * 64 + nf * 16 + ch];
      ad_c[nf] = a_dv[h * 64 + nf * 16 + ch];
    }
#pragma unroll
    for (int m = 0; m < 4; ++m) {
#pragma unroll
      for (int j = 0; j < 4; ++j) {
        float ps = 0.f, pd = 0.f;
#pragma unroll
        for (int nf = 0; nf < 4; ++nf) {
          float v = acc[m][nf][j];
          ps += v * as_c[nf];
          pd += v * ad_c[nf];
        }
#pragma unroll
        for (int off = 1; off < 16; off <<= 1) {
          ps += __shfl_xor(ps, off);
          pd += __shfl_xor(pd, off);
        }
        int rg = row0 + wrow * 64 + m * 16 + (lane >> 4) * 4 + j;
        if ((lane & 15) == 0 && rg < n) {
          asrcN[(size_t)rg * 4 + h] = ps;
          adstN[(size_t)rg * 4 + h] = pd;
        }
      }
    }
  }
}

// ---------------- edge-parallel softmax numerators: ex[e][h] ----------------
__global__ __launch_bounds__(256) void edge_ex_k(const int* __restrict__ col,
                                                 const int* __restrict__ dst2,
                                                 const float* __restrict__ asrcN,
                                                 const float* __restrict__ adstN,
                                                 float* __restrict__ ex, int EE) {
  int t = blockIdx.x * 256 + threadIdx.x;  // one per (e,h)
  if (t >= EE * 4) return;
  int e = t >> 2, h = t & 3;
  int s = col[e], d = dst2[e];
  float a = asrcN[(size_t)s * 4 + h] + adstN[(size_t)d * 4 + h];
  ex[t] = __expf(lrelu_f(a));  // softmax shift-invariant; |a| <~ 5 so no overflow
}

// ---------------- fused GAT aggregation + bias + LayerNorm + ELU ----------------
// MODE 0: LN(256) -> bf16 row written at (u16*)out + node*256 (packed [n,256])
// MODE 1: head-mean -> bias -> LN(64) -> ELU -> f32 out[node*64..]
template <int MODE>
__global__ __launch_bounds__(256) void gat_agg2_k(const u16* __restrict__ feat,
                                                  const float* __restrict__ ex,
                                                  const int* __restrict__ rowptr,
                                                  const int* __restrict__ col,
                                                  const float* __restrict__ bias,
                                                  const float* __restrict__ g,
                                                  const float* __restrict__ be,
                                                  void* __restrict__ out, int n) {
  int wave = threadIdx.x >> 6, lane = threadIdx.x & 63;
  int node = blockIdx.x * 4 + wave;
  if (node >= n) return;
  int h = lane >> 4;
  int s0 = rowptr[node], s1 = rowptr[node + 1];
  float ax = 0.f, ay = 0.f, az = 0.f, aw = 0.f, den = 0.f;
  int e = s0;
  for (; e + 4 <= s1; e += 4) {
    int sa = col[e + 0], sb = col[e + 1], sc = col[e + 2], sd = col[e + 3];
    float xa = ex[(size_t)(e + 0) * 4 + h];
    float xb = ex[(size_t)(e + 1) * 4 + h];
    float xc = ex[(size_t)(e + 2) * 4 + h];
    float xd = ex[(size_t)(e + 3) * 4 + h];
    u16x4 fa = *reinterpret_cast<const u16x4*>(&feat[(size_t)sa * 256 + lane * 4]);
    u16x4 fb = *reinterpret_cast<const u16x4*>(&feat[(size_t)sb * 256 + lane * 4]);
    u16x4 fc = *reinterpret_cast<const u16x4*>(&feat[(size_t)sc * 256 + lane * 4]);
    u16x4 fd = *reinterpret_cast<const u16x4*>(&feat[(size_t)sd * 256 + lane * 4]);
    den += (xa + xb) + (xc + xd);
    ax += xa * b2f(fa.x) + xb * b2f(fb.x) + xc * b2f(fc.x) + xd * b2f(fd.x);
    ay += xa * b2f(fa.y) + xb * b2f(fb.y) + xc * b2f(fc.y) + xd * b2f(fd.y);
    az += xa * b2f(fa.z) + xb * b2f(fb.z) + xc * b2f(fc.z) + xd * b2f(fd.z);
    aw += xa * b2f(fa.w) + xb * b2f(fb.w) + xc * b2f(fc.w) + xd * b2f(fd.w);
  }
  for (; e < s1; ++e) {
    int s = col[e];
    float x = ex[(size_t)e * 4 + h];
    den += x;
    u16x4 f = *reinterpret_cast<const u16x4*>(&feat[(size_t)s * 256 + lane * 4]);
    ax += x * b2f(f.x); ay += x * b2f(f.y); az += x * b2f(f.z); aw += x * b2f(f.w);
  }
  float inv = 1.f / den;  // self-loop guarantees den > 0
  ax *= inv; ay *= inv; az *= inv; aw *= inv;

  if (MODE == 0) {
    float4 b4 = *reinterpret_cast<const float4*>(&bias[lane * 4]);
    float vx = ax + b4.x, vy = ay + b4.y, vz = az + b4.z, vw = aw + b4.w;
    float s = vx + vy + vz + vw;
#pragma unroll
    for (int off = 1; off < 64; off <<= 1) s += __shfl_xor(s, off);
    float mu = s * (1.f / 256.f);
    float dx = vx - mu, dy = vy - mu, dz = vz - mu, dw = vw - mu;
    float q = dx * dx + dy * dy + dz * dz + dw * dw;
#pragma unroll
    for (int off = 1; off < 64; off <<= 1) q += __shfl_xor(q, off);
    float inv2 = rsqrtf(q * (1.f / 256.f) + 1e-5f);
    float4 gg = *reinterpret_cast<const float4*>(&g[lane * 4]);
    float4 bb = *reinterpret_cast<const float4*>(&be[lane * 4]);
    u16x4 o;
    o.x = f2b(elu_f(dx * inv2 * gg.x + bb.x));
    o.y = f2b(elu_f(dy * inv2 * gg.y + bb.y));
    o.z = f2b(elu_f(dz * inv2 * gg.z + bb.z));
    o.w = f2b(elu_f(dw * inv2 * gg.w + bb.w));
    u16* rowb = (u16*)out + (size_t)node * 256;
    *reinterpret_cast<u16x4*>(&rowb[lane * 4]) = o;
  } else {
    // head-mean: sum over h (lane bits 4,5)
    ax += __shfl_xor(ax, 16); ax += __shfl_xor(ax, 32);
    ay += __shfl_xor(ay, 16); ay += __shfl_xor(ay, 32);
    az += __shfl_xor(az, 16); az += __shfl_xor(az, 32);
    aw += __shfl_xor(aw, 16); aw += __shfl_xor(aw, 32);
    int qd = lane & 15;
    float4 b4 = *reinterpret_cast<const float4*>(&bias[qd * 4]);
    float vx = 0.25f * ax + b4.x, vy = 0.25f * ay + b4.y;
    float vz = 0.25f * az + b4.z, vw = 0.25f * aw + b4.w;
    // LN over 64 cols; each col replicated 4x across lanes -> divide by 256
    float s = vx + vy + vz + vw;
#pragma unroll
    for (int off = 1; off < 64; off <<= 1) s += __shfl_xor(s, off);
    float mu = s * (1.f / 256.f);
    float dx = vx - mu, dy = vy - mu, dz = vz - mu, dw = vw - mu;
    float q = dx * dx + dy * dy + dz * dz + dw * dw;
#pragma unroll
    for (int off = 1; off < 64; off <<= 1) q += __shfl_xor(q, off);
    float inv2 = rsqrtf(q * (1.f / 256.f) + 1e-5f);
    if (lane < 16) {
      float4 gg = *reinterpret_cast<const float4*>(&g[qd * 4]);
      float4 bb = *reinterpret_cast<const float4*>(&be[qd * 4]);
      float4 o;
      o.x = elu_f(dx * inv2 * gg.x + bb.x);
      o.y = elu_f(dy * inv2 * gg.y + bb.y);
      o.z = elu_f(dz * inv2 * gg.z + bb.z);
      o.w = elu_f(dw * inv2 * gg.w + bb.w);
      *reinterpret_cast<float4*>(&((float*)out)[(size_t)node * 64 + qd * 4]) = o;
    }
  }
}

// ---------------- value head: out[n,4] ----------------
__global__ __launch_bounds__(256) void value_head_k(const float* __restrict__ hh,
                                                    const float* __restrict__ vw1,
                                                    const float* __restrict__ vb1,
                                                    const float* __restrict__ vw2,
                                                    const float* __restrict__ vb2,
                                                    float* __restrict__ out, int n) {
  __shared__ float w1s[32 * 65];
  __shared__ float hs[4][64];
  __shared__ float vs[4][33];
  int tid = threadIdx.x;
  for (int i = tid; i < 2048; i += 256) w1s[(i >> 6) * 65 + (i & 63)] = vw1[i];
  int wave = tid >> 6, lane = tid & 63;
  int node = blockIdx.x * 4 + wave;
  int nc = node < n ? node : n - 1;
  hs[wave][lane] = hh[(size_t)nc * 64 + lane];
  __syncthreads();
  int j = lane & 31, half = lane >> 5;
  float p = 0.f;
#pragma unroll
  for (int c = 0; c < 32; ++c) p += hs[wave][half * 32 + c] * w1s[j * 65 + half * 32 + c];
  p += __shfl_xor(p, 32);
  float v = elu_f(p + vb1[j]);
  if (half == 0) vs[wave][j] = v;
  __syncthreads();
  if (lane < 4 && node < n) {
    float o = vb2[lane];
#pragma unroll
    for (int jj = 0; jj < 32; ++jj) o += vs[wave][jj] * vw2[lane * 32 + jj];
    out[(size_t)node * 4 + lane] = o;
  }
}

extern "C" void kernel_launch(void* const* d_in, const int* in_sizes, int n_in,
                              void* d_out, int out_size, void* d_ws, size_t ws_size,
                              hipStream_t stream) {
  const float* x      = (const float*)d_in[0];
  const int*   esrc   = (const int*)d_in[1];
  const int*   edst   = (const int*)d_in[2];
  const float* proj_w = (const float*)d_in[3];
  const float* proj_b = (const float*)d_in[4];
  const float* w[3]   = {(const float*)d_in[5],  (const float*)d_in[11], (const float*)d_in[17]};
  const float* a_s[3] = {(const float*)d_in[6],  (const float*)d_in[12], (const float*)d_in[18]};
  const float* a_d[3] = {(const float*)d_in[7],  (const float*)d_in[13], (const float*)d_in[19]};
  const float* bb[3]  = {(const float*)d_in[8],  (const float*)d_in[14], (const float*)d_in[20]};
  const float* gg[3]  = {(const float*)d_in[9],  (const float*)d_in[15], (const float*)d_in[21]};
  const float* be[3]  = {(const float*)d_in[10], (const float*)d_in[16], (const float*)d_in[22]};
  const float* vw1 = (const float*)d_in[23];
  const float* vb1 = (const float*)d_in[24];
  const float* vw2 = (const float*)d_in[25];
  const float* vb2 = (const float*)d_in[26];
  float* outp = (float*)d_out;

  const int n = in_sizes[0] / 128;
  const int E = in_sizes[1];
  const int EE = E + n;
  const int nbl = (n + 255) / 256;  // scan blocks (<=1024 supported)

  // ---- workspace layout ----
  char* p = (char*)d_ws;
  auto alloc = [&](size_t bytes) { char* r = p; p += (bytes + 255) & ~(size_t)255; return r; };
  u16*   hA    = (u16*)alloc((size_t)n * 512);     // packed bf16 [n,256] layer input; hfinal f32 [n,64] later
  u16*   featB = (u16*)alloc((size_t)n * 512);     // bf16 [n,256] gemm output; x bf16 first
  float* ex    = (float*)alloc((size_t)EE * 16);   // softmax numerators [EE,4]
  float* asrcN = (float*)alloc((size_t)n * 16);
  float* adstN = (float*)alloc((size_t)n * 16);
  u16* wbp = (u16*)alloc(64 * 128 * 2);
  u16* wb[3];
  wb[0] = (u16*)alloc(256 * 64 * 2);
  wb[1] = (u16*)alloc(256 * 256 * 2);
  wb[2] = (u16*)alloc(256 * 256 * 2);
  int* deg    = (int*)alloc((size_t)n * 4);
  int* rowptr = (int*)alloc((size_t)(n + 1) * 4);
  int* cursor = (int*)alloc((size_t)n * 4);
  int* col    = (int*)alloc((size_t)EE * 4);
  int* dst2   = (int*)alloc((size_t)EE * 4);
  int* bsum   = (int*)alloc((size_t)nbl * 4);
  float* hfinal = (float*)hA;  // f32 [n,64]; hA dead after layer-2 gemm

  // ---- CSR build ----
  hipMemsetAsync(deg, 0, (size_t)n * sizeof(int), stream);
  deg_count_k<<<(EE + 255) / 256, 256, 0, stream>>>(esrc, edst, E, n, deg);
  block_sum_k<<<nbl, 256, 0, stream>>>(deg, bsum, n);
  scan_bsum_k<<<1, 1024, 0, stream>>>(bsum, nbl);
  block_scan_k<<<nbl, 256, 0, stream>>>(deg, bsum, rowptr, cursor, n);
  scatter_k<<<(EE + 255) / 256, 256, 0, stream>>>(esrc, edst, E, n, cursor, col, dst2);

  // ---- dtype conversions (single dispatch) ----
  const int nx8 = n * 16;  // n*128/8 vector-8 groups
  cvt_all_k<<<(nx8 + 155648 + 255) / 256, 256, 0, stream>>>(x, featB, nx8, proj_w, w[0], w[1], w[2],
                                                            wbp, wb[0], wb[1], wb[2]);

  const int nb4 = (n + 3) / 4;
  const int nbg = (n + 127) / 128;
  dim3 blk(256);

  // ---- projection: hA[n,0..63] = elu(x @ proj_w^T + proj_b), bf16, ldc=256 ----
  gemm_bf16_k<1, 0><<<dim3(nbg, 1), blk, 0, stream>>>(featB, 128, wbp, proj_b, hA, 256, n, 128, 64,
                                                      nullptr, nullptr, nullptr, nullptr);

  const int Kin[3] = {64, 256, 256};
  for (int i = 0; i < 3; ++i) {
    // feat GEMM with fused attention-score epilogue
    gemm_bf16_k<0, 1><<<dim3(nbg, 2), blk, 0, stream>>>(hA, 256, wb[i], nullptr, featB, 256, n,
                                                        Kin[i], 256, a_s[i], a_d[i], asrcN, adstN);
    edge_ex_k<<<((size_t)EE * 4 + 255) / 256, 256, 0, stream>>>(col, dst2, asrcN, adstN, ex, EE);
    if (i < 2) {
      gat_agg2_k<0><<<nb4, blk, 0, stream>>>(featB, ex, rowptr, col, bb[i], gg[i], be[i], (void*)hA, n);
    } else {
      gat_agg2_k<1><<<nb4, blk, 0, stream>>>(featB, ex, rowptr, col, bb[i], gg[i], be[i], (void*)hfinal, n);
    }
  }

  // ---- value head ----
  value_head_k<<<nb4, blk, 0, stream>>>(hfinal, vw1, vb1, vw2, vb2, outp, n);
}

// Round 7
// 426.088 us; speedup vs baseline: 1.2998x; 1.0859x over previous
//
#include <hip/hip_runtime.h>

typedef unsigned short u16;
typedef u16 u16x4 __attribute__((ext_vector_type(4)));
typedef short short8 __attribute__((ext_vector_type(8)));
typedef float f32x4 __attribute__((ext_vector_type(4)));

__device__ __forceinline__ float elu_f(float x) { return x > 0.f ? x : expm1f(x); }
__device__ __forceinline__ float lrelu_f(float x) { return x > 0.f ? x : 0.2f * x; }

__device__ __forceinline__ u16 f2b(float f) {
  union { float f; unsigned u; } v; v.f = f;
  unsigned r = v.u + 0x7FFF + ((v.u >> 16) & 1);
  return (u16)(r >> 16);
}
__device__ __forceinline__ float b2f(u16 u) {
  union { unsigned u; float f; } v; v.u = ((unsigned)u) << 16; return v.f;
}

// ---------------- CSR build ----------------
__global__ void deg_count_k(const int* __restrict__ src, const int* __restrict__ dst,
                            int E, int n, int* __restrict__ deg) {
  int e = blockIdx.x * blockDim.x + threadIdx.x;
  if (e < E) {
    atomicAdd(&deg[dst[e]], 1);
  } else if (e < E + n) {
    atomicAdd(&deg[e - E], 1);  // self loop
  }
}

__global__ __launch_bounds__(256) void block_sum_k(const int* __restrict__ deg,
                                                   int* __restrict__ bsum, int n) {
  int i = blockIdx.x * 256 + threadIdx.x;
  int v = (i < n) ? deg[i] : 0;
#pragma unroll
  for (int off = 1; off < 64; off <<= 1) v += __shfl_xor(v, off);
  __shared__ int ws[4];
  if ((threadIdx.x & 63) == 0) ws[threadIdx.x >> 6] = v;
  __syncthreads();
  if (threadIdx.x == 0) bsum[blockIdx.x] = ws[0] + ws[1] + ws[2] + ws[3];
}

__global__ void scan_bsum_k(int* __restrict__ bsum, int nb) {
  __shared__ int s[1024];
  int tid = threadIdx.x;
  int v = (tid < nb) ? bsum[tid] : 0;
  s[tid] = v;
  __syncthreads();
  for (int off = 1; off < 1024; off <<= 1) {
    int t = (tid >= off) ? s[tid - off] : 0;
    __syncthreads();
    s[tid] += t;
    __syncthreads();
  }
  if (tid < nb) bsum[tid] = s[tid] - v;  // exclusive
}

__global__ __launch_bounds__(256) void block_scan_k(const int* __restrict__ deg,
                                                    const int* __restrict__ bsum,
                                                    int* __restrict__ rowptr,
                                                    int* __restrict__ cursor, int n) {
  int i = blockIdx.x * 256 + threadIdx.x;
  int lane = threadIdx.x & 63, w = threadIdx.x >> 6;
  int v = (i < n) ? deg[i] : 0;
  int x = v;
#pragma unroll
  for (int off = 1; off < 64; off <<= 1) {
    int t = __shfl_up(x, off);
    if (lane >= off) x += t;
  }
  __shared__ int ws[4];
  if (lane == 63) ws[w] = x;
  __syncthreads();
  int add = bsum[blockIdx.x];
  for (int j = 0; j < w; ++j) add += ws[j];
  int excl = x - v + add;
  if (i < n) {
    cursor[i] = excl;
    rowptr[i + 1] = excl + v;
  }
  if (i == 0) rowptr[0] = 0;
}

__global__ void scatter_k(const int* __restrict__ src, const int* __restrict__ dst,
                          int E, int n, int* __restrict__ cursor,
                          int* __restrict__ col, int* __restrict__ dst2) {
  int e = blockIdx.x * blockDim.x + threadIdx.x;
  if (e < E) {
    int d = dst[e];
    int pos = atomicAdd(&cursor[d], 1);
    col[pos] = src[e];
    dst2[pos] = d;
  } else if (e < E + n) {
    int d = e - E;
    int pos = atomicAdd(&cursor[d], 1);
    col[pos] = d;  // self loop
    dst2[pos] = d;
  }
}

// ---------------- all conversions (x vectorized + 4 weight mats) in ONE dispatch ----------------
__global__ __launch_bounds__(256) void cvt_all_k(const float* __restrict__ x, u16* __restrict__ xb,
                                                 int nx8,
                                                 const float* __restrict__ pw,
                                                 const float* __restrict__ w0,
                                                 const float* __restrict__ w1,
                                                 const float* __restrict__ w2,
                                                 u16* __restrict__ dp, u16* __restrict__ d0,
                                                 u16* __restrict__ d1, u16* __restrict__ d2) {
  int i = blockIdx.x * 256 + threadIdx.x;
  if (i < nx8) {
    int j = i * 8;
    float4 a = *reinterpret_cast<const float4*>(&x[j]);
    float4 b = *reinterpret_cast<const float4*>(&x[j + 4]);
    u16x4 o0, o1;
    o0.x = f2b(a.x); o0.y = f2b(a.y); o0.z = f2b(a.z); o0.w = f2b(a.w);
    o1.x = f2b(b.x); o1.y = f2b(b.y); o1.z = f2b(b.z); o1.w = f2b(b.w);
    *reinterpret_cast<u16x4*>(&xb[j]) = o0;
    *reinterpret_cast<u16x4*>(&xb[j + 4]) = o1;
  } else {
    int j = i - nx8;
    if (j < 8192) dp[j] = f2b(pw[j]);
    else if (j < 24576) d0[j - 8192] = f2b(w0[j - 8192]);
    else if (j < 90112) d1[j - 24576] = f2b(w1[j - 24576]);
    else if (j < 155648) d2[j - 90112] = f2b(w2[j - 90112]);
  }
}

// ---------------- bf16 MFMA GEMM, 128x128 tile (proj only) ----------------
template <int BIASELU>
__global__ __launch_bounds__(256) void gemm_bf16_k(const u16* __restrict__ A, int lda,
                                                   const u16* __restrict__ W,
                                                   const float* __restrict__ bias,
                                                   u16* __restrict__ Cb, int ldc,
                                                   int n, int K, int ncols) {
  __shared__ int4 Abuf[1024];
  __shared__ int4 Bbuf[1024];
  char* Asb = (char*)Abuf;
  char* Bsb = (char*)Bbuf;
  const int t = threadIdx.x;
  const int lane = t & 63, w = t >> 6;
  const int wrow = w >> 1, wcol = w & 1;
  const int row0 = blockIdx.x * 128, col0 = blockIdx.y * 128;
  f32x4 acc[4][4];
#pragma unroll
  for (int m = 0; m < 4; ++m)
#pragma unroll
    for (int nf = 0; nf < 4; ++nf) acc[m][nf] = (f32x4){0.f, 0.f, 0.f, 0.f};

  for (int k0 = 0; k0 < K; k0 += 64) {
#pragma unroll
    for (int i = 0; i < 4; ++i) {
      int ci = i * 256 + t;
      int r = ci >> 3;
      int b = (ci & 7) << 4;
      int sw = b ^ ((r & 7) << 4);
      int ar = row0 + r; ar = ar < n ? ar : n - 1;
      int4 av = *reinterpret_cast<const int4*>(&A[(size_t)ar * lda + k0 + (b >> 1)]);
      *reinterpret_cast<int4*>(Asb + r * 128 + sw) = av;
      int wr = col0 + r; wr = wr < ncols ? wr : ncols - 1;
      int4 wv = *reinterpret_cast<const int4*>(&W[(size_t)wr * K + k0 + (b >> 1)]);
      *reinterpret_cast<int4*>(Bsb + r * 128 + sw) = wv;
    }
    __syncthreads();
#pragma unroll
    for (int ks = 0; ks < 2; ++ks) {
      short8 af[4], bf[4];
      int kb = ks * 64 + ((lane >> 4) << 4);
#pragma unroll
      for (int m = 0; m < 4; ++m) {
        int r = wrow * 64 + m * 16 + (lane & 15);
        af[m] = *reinterpret_cast<const short8*>(Asb + r * 128 + (kb ^ ((r & 7) << 4)));
      }
#pragma unroll
      for (int nf = 0; nf < 4; ++nf) {
        int r = wcol * 64 + nf * 16 + (lane & 15);
        bf[nf] = *reinterpret_cast<const short8*>(Bsb + r * 128 + (kb ^ ((r & 7) << 4)));
      }
#pragma unroll
      for (int m = 0; m < 4; ++m)
#pragma unroll
        for (int nf = 0; nf < 4; ++nf)
          acc[m][nf] = __builtin_amdgcn_mfma_f32_16x16x32_bf16(af[m], bf[nf], acc[m][nf], 0, 0, 0);
    }
    __syncthreads();
  }
#pragma unroll
  for (int m = 0; m < 4; ++m) {
#pragma unroll
    for (int j = 0; j < 4; ++j) {
      int rg = row0 + wrow * 64 + m * 16 + (lane >> 4) * 4 + j;
      if (rg >= n) continue;
#pragma unroll
      for (int nf = 0; nf < 4; ++nf) {
        int cg = col0 + wcol * 64 + nf * 16 + (lane & 15);
        if (cg >= ncols) continue;
        float v = acc[m][nf][j];
        if (BIASELU) v = elu_f(v + bias[cg]);
        Cb[(size_t)rg * ldc + cg] = f2b(v);
      }
    }
  }
}

// ---------------- bf16 MFMA GEMM, 128x256 tile (ncols==256), fused attn scores ----------------
// 512 threads, 8 waves (wrow=w>>2 in 0..1, wcol=w&3 in 0..3). head = wcol.
__global__ __launch_bounds__(512) void gemm2_k(const u16* __restrict__ A, int lda,
                                               const u16* __restrict__ W,
                                               u16* __restrict__ Cb,
                                               int n, int K,
                                               const float* __restrict__ a_sv,
                                               const float* __restrict__ a_dv,
                                               float* __restrict__ asrcN,
                                               float* __restrict__ adstN) {
  __shared__ char Asb[128 * 128];  // 128 rows x 128B, XOR-swizzled
  __shared__ char Bsb[256 * 128];  // 256 rows x 128B
  const int t = threadIdx.x;
  const int lane = t & 63, w = t >> 6;
  const int wrow = w >> 2, wcol = w & 3;
  const int row0 = blockIdx.x * 128;
  f32x4 acc[4][4];
#pragma unroll
  for (int m = 0; m < 4; ++m)
#pragma unroll
    for (int nf = 0; nf < 4; ++nf) acc[m][nf] = (f32x4){0.f, 0.f, 0.f, 0.f};

  for (int k0 = 0; k0 < K; k0 += 64) {
#pragma unroll
    for (int i = 0; i < 2; ++i) {  // A: 1024 chunks
      int ci = i * 512 + t;
      int r = ci >> 3;
      int b = (ci & 7) << 4;
      int sw = b ^ ((r & 7) << 4);
      int ar = row0 + r; ar = ar < n ? ar : n - 1;
      int4 av = *reinterpret_cast<const int4*>(&A[(size_t)ar * lda + k0 + (b >> 1)]);
      *reinterpret_cast<int4*>(Asb + r * 128 + sw) = av;
    }
#pragma unroll
    for (int i = 0; i < 4; ++i) {  // B: 2048 chunks (256 rows)
      int ci = i * 512 + t;
      int r = ci >> 3;
      int b = (ci & 7) << 4;
      int sw = b ^ ((r & 7) << 4);
      int4 wv = *reinterpret_cast<const int4*>(&W[(size_t)r * K + k0 + (b >> 1)]);
      *reinterpret_cast<int4*>(Bsb + r * 128 + sw) = wv;
    }
    __syncthreads();
#pragma unroll
    for (int ks = 0; ks < 2; ++ks) {
      short8 af[4], bf[4];
      int kb = ks * 64 + ((lane >> 4) << 4);
#pragma unroll
      for (int m = 0; m < 4; ++m) {
        int r = wrow * 64 + m * 16 + (lane & 15);
        af[m] = *reinterpret_cast<const short8*>(Asb + r * 128 + (kb ^ ((r & 7) << 4)));
      }
#pragma unroll
      for (int nf = 0; nf < 4; ++nf) {
        int r = wcol * 64 + nf * 16 + (lane & 15);
        bf[nf] = *reinterpret_cast<const short8*>(Bsb + r * 128 + (kb ^ ((r & 7) << 4)));
      }
#pragma unroll
      for (int m = 0; m < 4; ++m)
#pragma unroll
        for (int nf = 0; nf < 4; ++nf)
          acc[m][nf] = __builtin_amdgcn_mfma_f32_16x16x32_bf16(af[m], bf[nf], acc[m][nf], 0, 0, 0);
    }
    __syncthreads();
  }
  // C write: col = wcol*64 + nf*16 + (lane&15); row = wrow*64 + m*16 + (lane>>4)*4 + j
#pragma unroll
  for (int m = 0; m < 4; ++m) {
#pragma unroll
    for (int j = 0; j < 4; ++j) {
      int rg = row0 + wrow * 64 + m * 16 + (lane >> 4) * 4 + j;
      if (rg >= n) continue;
#pragma unroll
      for (int nf = 0; nf < 4; ++nf) {
        int cg = wcol * 64 + nf * 16 + (lane & 15);
        Cb[(size_t)rg * 256 + cg] = f2b(acc[m][nf][j]);
      }
    }
  }
  // fused attention scores: this wave's 64-col block = head wcol
  {
    int h = wcol;
    int ch = lane & 15;
    float as_c[4], ad_c[4];
#pragma unroll
    for (int nf = 0; nf < 4; ++nf) {
      as_c[nf] = a_sv[h * 64 + nf * 16 + ch];
      ad_c[nf] = a_dv[h * 64 + nf * 16 + ch];
    }
#pragma unroll
    for (int m = 0; m < 4; ++m) {
#pragma unroll
      for (int j = 0; j < 4; ++j) {
        float ps = 0.f, pd = 0.f;
#pragma unroll
        for (int nf = 0; nf < 4; ++nf) {
          float v = acc[m][nf][j];
          ps += v * as_c[nf];
          pd += v * ad_c[nf];
        }
#pragma unroll
        for (int off = 1; off < 16; off <<= 1) {
          ps += __shfl_xor(ps, off);
          pd += __shfl_xor(pd, off);
        }
        int rg = row0 + wrow * 64 + m * 16 + (lane >> 4) * 4 + j;
        if ((lane & 15) == 0 && rg < n) {
          asrcN[(size_t)rg * 4 + h] = ps;
          adstN[(size_t)rg * 4 + h] = pd;
        }
      }
    }
  }
}

// ---------------- edge-parallel softmax numerators, transposed: exT[h][e] ----------------
__global__ __launch_bounds__(256) void edge_ex2_k(const int* __restrict__ col,
                                                  const int* __restrict__ dst2,
                                                  const float* __restrict__ asrcN,
                                                  const float* __restrict__ adstN,
                                                  float* __restrict__ exT, int eep, int EE) {
  int e = blockIdx.x * 256 + threadIdx.x;
  if (e >= EE) return;
  int s = col[e], d = dst2[e];
  float4 as = *reinterpret_cast<const float4*>(&asrcN[(size_t)s * 4]);
  float4 ad = *reinterpret_cast<const float4*>(&adstN[(size_t)d * 4]);
  exT[e]            = __expf(lrelu_f(as.x + ad.x));  // softmax shift-invariant; |a| <~ 5
  exT[eep + e]      = __expf(lrelu_f(as.y + ad.y));
  exT[2 * eep + e]  = __expf(lrelu_f(as.z + ad.z));
  exT[3 * eep + e]  = __expf(lrelu_f(as.w + ad.w));
}

// ---------------- fused GAT aggregation + bias + LayerNorm + ELU (8-deep pipelined) ----------------
// MODE 0: LN(256) -> bf16 row at (u16*)out + node*256
// MODE 1: head-mean -> bias -> LN(64) -> ELU -> f32 out[node*64..]
template <int MODE>
__global__ __launch_bounds__(256) void gat_agg4_k(const u16* __restrict__ feat,
                                                  const float* __restrict__ exT, int eep,
                                                  const int* __restrict__ rowptr,
                                                  const int* __restrict__ col,
                                                  const float* __restrict__ bias,
                                                  const float* __restrict__ g,
                                                  const float* __restrict__ be,
                                                  void* __restrict__ out, int n) {
  int wave = threadIdx.x >> 6, lane = threadIdx.x & 63;
  int node = blockIdx.x * 4 + wave;
  if (node >= n) return;
  int h = lane >> 4;
  const float* exh = exT + (size_t)h * eep;
  int s0 = rowptr[node], s1 = rowptr[node + 1];
  float ax = 0.f, ay = 0.f, az = 0.f, aw = 0.f, den = 0.f;
  int e = s0;
  // 8-deep: two independent 4-groups, all loads issued before FMAs
  for (; e + 8 <= s1; e += 8) {
    int p0 = col[e + 0], p1 = col[e + 1], p2 = col[e + 2], p3 = col[e + 3];
    int q0 = col[e + 4], q1 = col[e + 5], q2 = col[e + 6], q3 = col[e + 7];
    float u0 = exh[e + 0], u1 = exh[e + 1], u2 = exh[e + 2], u3 = exh[e + 3];
    float v0 = exh[e + 4], v1 = exh[e + 5], v2 = exh[e + 6], v3 = exh[e + 7];
    u16x4 fp0 = *reinterpret_cast<const u16x4*>(&feat[(size_t)p0 * 256 + lane * 4]);
    u16x4 fp1 = *reinterpret_cast<const u16x4*>(&feat[(size_t)p1 * 256 + lane * 4]);
    u16x4 fp2 = *reinterpret_cast<const u16x4*>(&feat[(size_t)p2 * 256 + lane * 4]);
    u16x4 fp3 = *reinterpret_cast<const u16x4*>(&feat[(size_t)p3 * 256 + lane * 4]);
    u16x4 fq0 = *reinterpret_cast<const u16x4*>(&feat[(size_t)q0 * 256 + lane * 4]);
    u16x4 fq1 = *reinterpret_cast<const u16x4*>(&feat[(size_t)q1 * 256 + lane * 4]);
    u16x4 fq2 = *reinterpret_cast<const u16x4*>(&feat[(size_t)q2 * 256 + lane * 4]);
    u16x4 fq3 = *reinterpret_cast<const u16x4*>(&feat[(size_t)q3 * 256 + lane * 4]);
    den += ((u0 + u1) + (u2 + u3)) + ((v0 + v1) + (v2 + v3));
    ax += u0 * b2f(fp0.x) + u1 * b2f(fp1.x) + u2 * b2f(fp2.x) + u3 * b2f(fp3.x);
    ay += u0 * b2f(fp0.y) + u1 * b2f(fp1.y) + u2 * b2f(fp2.y) + u3 * b2f(fp3.y);
    az += u0 * b2f(fp0.z) + u1 * b2f(fp1.z) + u2 * b2f(fp2.z) + u3 * b2f(fp3.z);
    aw += u0 * b2f(fp0.w) + u1 * b2f(fp1.w) + u2 * b2f(fp2.w) + u3 * b2f(fp3.w);
    ax += v0 * b2f(fq0.x) + v1 * b2f(fq1.x) + v2 * b2f(fq2.x) + v3 * b2f(fq3.x);
    ay += v0 * b2f(fq0.y) + v1 * b2f(fq1.y) + v2 * b2f(fq2.y) + v3 * b2f(fq3.y);
    az += v0 * b2f(fq0.z) + v1 * b2f(fq1.z) + v2 * b2f(fq2.z) + v3 * b2f(fq3.z);
    aw += v0 * b2f(fq0.w) + v1 * b2f(fq1.w) + v2 * b2f(fq2.w) + v3 * b2f(fq3.w);
  }
  for (; e + 4 <= s1; e += 4) {
    int p0 = col[e + 0], p1 = col[e + 1], p2 = col[e + 2], p3 = col[e + 3];
    float u0 = exh[e + 0], u1 = exh[e + 1], u2 = exh[e + 2], u3 = exh[e + 3];
    u16x4 fp0 = *reinterpret_cast<const u16x4*>(&feat[(size_t)p0 * 256 + lane * 4]);
    u16x4 fp1 = *reinterpret_cast<const u16x4*>(&feat[(size_t)p1 * 256 + lane * 4]);
    u16x4 fp2 = *reinterpret_cast<const u16x4*>(&feat[(size_t)p2 * 256 + lane * 4]);
    u16x4 fp3 = *reinterpret_cast<const u16x4*>(&feat[(size_t)p3 * 256 + lane * 4]);
    den += (u0 + u1) + (u2 + u3);
    ax += u0 * b2f(fp0.x) + u1 * b2f(fp1.x) + u2 * b2f(fp2.x) + u3 * b2f(fp3.x);
    ay += u0 * b2f(fp0.y) + u1 * b2f(fp1.y) + u2 * b2f(fp2.y) + u3 * b2f(fp3.y);
    az += u0 * b2f(fp0.z) + u1 * b2f(fp1.z) + u2 * b2f(fp2.z) + u3 * b2f(fp3.z);
    aw += u0 * b2f(fp0.w) + u1 * b2f(fp1.w) + u2 * b2f(fp2.w) + u3 * b2f(fp3.w);
  }
  for (; e < s1; ++e) {
    int s = col[e];
    float x = exh[e];
    den += x;
    u16x4 f = *reinterpret_cast<const u16x4*>(&feat[(size_t)s * 256 + lane * 4]);
    ax += x * b2f(f.x); ay += x * b2f(f.y); az += x * b2f(f.z); aw += x * b2f(f.w);
  }
  float inv = 1.f / den;  // self-loop guarantees den > 0
  ax *= inv; ay *= inv; az *= inv; aw *= inv;

  if (MODE == 0) {
    float4 b4 = *reinterpret_cast<const float4*>(&bias[lane * 4]);
    float vx = ax + b4.x, vy = ay + b4.y, vz = az + b4.z, vw = aw + b4.w;
    float s = vx + vy + vz + vw;
#pragma unroll
    for (int off = 1; off < 64; off <<= 1) s += __shfl_xor(s, off);
    float mu = s * (1.f / 256.f);
    float dx = vx - mu, dy = vy - mu, dz = vz - mu, dw = vw - mu;
    float q = dx * dx + dy * dy + dz * dz + dw * dw;
#pragma unroll
    for (int off = 1; off < 64; off <<= 1) q += __shfl_xor(q, off);
    float inv2 = rsqrtf(q * (1.f / 256.f) + 1e-5f);
    float4 gg = *reinterpret_cast<const float4*>(&g[lane * 4]);
    float4 bb = *reinterpret_cast<const float4*>(&be[lane * 4]);
    u16x4 o;
    o.x = f2b(elu_f(dx * inv2 * gg.x + bb.x));
    o.y = f2b(elu_f(dy * inv2 * gg.y + bb.y));
    o.z = f2b(elu_f(dz * inv2 * gg.z + bb.z));
    o.w = f2b(elu_f(dw * inv2 * gg.w + bb.w));
    u16* rowb = (u16*)out + (size_t)node * 256;
    *reinterpret_cast<u16x4*>(&rowb[lane * 4]) = o;
  } else {
    ax += __shfl_xor(ax, 16); ax += __shfl_xor(ax, 32);
    ay += __shfl_xor(ay, 16); ay += __shfl_xor(ay, 32);
    az += __shfl_xor(az, 16); az += __shfl_xor(az, 32);
    aw += __shfl_xor(aw, 16); aw += __shfl_xor(aw, 32);
    int qd = lane & 15;
    float4 b4 = *reinterpret_cast<const float4*>(&bias[qd * 4]);
    float vx = 0.25f * ax + b4.x, vy = 0.25f * ay + b4.y;
    float vz = 0.25f * az + b4.z, vw = 0.25f * aw + b4.w;
    float s = vx + vy + vz + vw;
#pragma unroll
    for (int off = 1; off < 64; off <<= 1) s += __shfl_xor(s, off);
    float mu = s * (1.f / 256.f);
    float dx = vx - mu, dy = vy - mu, dz = vz - mu, dw = vw - mu;
    float q = dx * dx + dy * dy + dz * dz + dw * dw;
#pragma unroll
    for (int off = 1; off < 64; off <<= 1) q += __shfl_xor(q, off);
    float inv2 = rsqrtf(q * (1.f / 256.f) + 1e-5f);
    if (lane < 16) {
      float4 gg = *reinterpret_cast<const float4*>(&g[qd * 4]);
      float4 bb = *reinterpret_cast<const float4*>(&be[qd * 4]);
      float4 o;
      o.x = elu_f(dx * inv2 * gg.x + bb.x);
      o.y = elu_f(dy * inv2 * gg.y + bb.y);
      o.z = elu_f(dz * inv2 * gg.z + bb.z);
      o.w = elu_f(dw * inv2 * gg.w + bb.w);
      *reinterpret_cast<float4*>(&((float*)out)[(size_t)node * 64 + qd * 4]) = o;
    }
  }
}

// ---------------- value head: out[n,4] ----------------
__global__ __launch_bounds__(256) void value_head_k(const float* __restrict__ hh,
                                                    const float* __restrict__ vw1,
                                                    const float* __restrict__ vb1,
                                                    const float* __restrict__ vw2,
                                                    const float* __restrict__ vb2,
                                                    float* __restrict__ out, int n) {
  __shared__ float w1s[32 * 65];
  __shared__ float hs[4][64];
  __shared__ float vs[4][33];
  int tid = threadIdx.x;
  for (int i = tid; i < 2048; i += 256) w1s[(i >> 6) * 65 + (i & 63)] = vw1[i];
  int wave = tid >> 6, lane = tid & 63;
  int node = blockIdx.x * 4 + wave;
  int nc = node < n ? node : n - 1;
  hs[wave][lane] = hh[(size_t)nc * 64 + lane];
  __syncthreads();
  int j = lane & 31, half = lane >> 5;
  float p = 0.f;
#pragma unroll
  for (int c = 0; c < 32; ++c) p += hs[wave][half * 32 + c] * w1s[j * 65 + half * 32 + c];
  p += __shfl_xor(p, 32);
  float v = elu_f(p + vb1[j]);
  if (half == 0) vs[wave][j] = v;
  __syncthreads();
  if (lane < 4 && node < n) {
    float o = vb2[lane];
#pragma unroll
    for (int jj = 0; jj < 32; ++jj) o += vs[wave][jj] * vw2[lane * 32 + jj];
    out[(size_t)node * 4 + lane] = o;
  }
}

extern "C" void kernel_launch(void* const* d_in, const int* in_sizes, int n_in,
                              void* d_out, int out_size, void* d_ws, size_t ws_size,
                              hipStream_t stream) {
  const float* x      = (const float*)d_in[0];
  const int*   esrc   = (const int*)d_in[1];
  const int*   edst   = (const int*)d_in[2];
  const float* proj_w = (const float*)d_in[3];
  const float* proj_b = (const float*)d_in[4];
  const float* w[3]   = {(const float*)d_in[5],  (const float*)d_in[11], (const float*)d_in[17]};
  const float* a_s[3] = {(const float*)d_in[6],  (const float*)d_in[12], (const float*)d_in[18]};
  const float* a_d[3] = {(const float*)d_in[7],  (const float*)d_in[13], (const float*)d_in[19]};
  const float* bb[3]  = {(const float*)d_in[8],  (const float*)d_in[14], (const float*)d_in[20]};
  const float* gg[3]  = {(const float*)d_in[9],  (const float*)d_in[15], (const float*)d_in[21]};
  const float* be[3]  = {(const float*)d_in[10], (const float*)d_in[16], (const float*)d_in[22]};
  const float* vw1 = (const float*)d_in[23];
  const float* vb1 = (const float*)d_in[24];
  const float* vw2 = (const float*)d_in[25];
  const float* vb2 = (const float*)d_in[26];
  float* outp = (float*)d_out;

  const int n = in_sizes[0] / 128;
  const int E = in_sizes[1];
  const int EE = E + n;
  const int eep = (EE + 255) & ~255;
  const int nbl = (n + 255) / 256;

  // ---- workspace layout ----
  char* p = (char*)d_ws;
  auto alloc = [&](size_t bytes) { char* r = p; p += (bytes + 255) & ~(size_t)255; return r; };
  u16*   hA    = (u16*)alloc((size_t)n * 512);     // packed bf16 [n,256]; hfinal f32 [n,64] later
  u16*   featB = (u16*)alloc((size_t)n * 512);     // bf16 [n,256] gemm output; x bf16 first
  float* exT   = (float*)alloc((size_t)eep * 16);  // transposed numerators [4][eep]
  float* asrcN = (float*)alloc((size_t)n * 16);
  float* adstN = (float*)alloc((size_t)n * 16);
  u16* wbp = (u16*)alloc(64 * 128 * 2);
  u16* wb[3];
  wb[0] = (u16*)alloc(256 * 64 * 2);
  wb[1] = (u16*)alloc(256 * 256 * 2);
  wb[2] = (u16*)alloc(256 * 256 * 2);
  int* deg    = (int*)alloc((size_t)n * 4);
  int* rowptr = (int*)alloc((size_t)(n + 1) * 4);
  int* cursor = (int*)alloc((size_t)n * 4);
  int* col    = (int*)alloc((size_t)EE * 4);
  int* dst2   = (int*)alloc((size_t)EE * 4);
  int* bsum   = (int*)alloc((size_t)nbl * 4);
  float* hfinal = (float*)hA;  // f32 [n,64]; hA dead after layer-2 gemm

  // ---- CSR build ----
  hipMemsetAsync(deg, 0, (size_t)n * sizeof(int), stream);
  deg_count_k<<<(EE + 255) / 256, 256, 0, stream>>>(esrc, edst, E, n, deg);
  block_sum_k<<<nbl, 256, 0, stream>>>(deg, bsum, n);
  scan_bsum_k<<<1, 1024, 0, stream>>>(bsum, nbl);
  block_scan_k<<<nbl, 256, 0, stream>>>(deg, bsum, rowptr, cursor, n);
  scatter_k<<<(EE + 255) / 256, 256, 0, stream>>>(esrc, edst, E, n, cursor, col, dst2);

  // ---- dtype conversions (single dispatch) ----
  const int nx8 = n * 16;
  cvt_all_k<<<(nx8 + 155648 + 255) / 256, 256, 0, stream>>>(x, featB, nx8, proj_w, w[0], w[1], w[2],
                                                            wbp, wb[0], wb[1], wb[2]);

  const int nb4 = (n + 3) / 4;
  const int nbg = (n + 127) / 128;
  dim3 blk(256);

  // ---- projection: hA[n,0..63] = elu(x @ proj_w^T + proj_b), bf16, ldc=256 ----
  gemm_bf16_k<1><<<dim3(nbg, 1), blk, 0, stream>>>(featB, 128, wbp, proj_b, hA, 256, n, 128, 64);

  const int Kin[3] = {64, 256, 256};
  for (int i = 0; i < 3; ++i) {
    gemm2_k<<<nbg, 512, 0, stream>>>(hA, 256, wb[i], featB, n, Kin[i],
                                     a_s[i], a_d[i], asrcN, adstN);
    edge_ex2_k<<<(EE + 255) / 256, 256, 0, stream>>>(col, dst2, asrcN, adstN, exT, eep, EE);
    if (i < 2) {
      gat_agg4_k<0><<<nb4, blk, 0, stream>>>(featB, exT, eep, rowptr, col, bb[i], gg[i], be[i], (void*)hA, n);
    } else {
      gat_agg4_k<1><<<nb4, blk, 0, stream>>>(featB, exT, eep, rowptr, col, bb[i], gg[i], be[i], (void*)hfinal, n);
    }
  }

  // ---- value head ----
  value_head_k<<<nb4, blk, 0, stream>>>(hfinal, vw1, vb1, vw2, vb2, outp, n);
}

// Round 9
// 400.049 us; speedup vs baseline: 1.3844x; 1.0651x over previous
//
#include <hip/hip_runtime.h>

typedef unsigned short u16;
typedef u16 u16x4 __attribute__((ext_vector_type(4)));
typedef short short8 __attribute__((ext_vector_type(8)));
typedef float f32x4 __attribute__((ext_vector_type(4)));

__device__ __forceinline__ float elu_f(float x) { return x > 0.f ? x : expm1f(x); }
__device__ __forceinline__ float lrelu_f(float x) { return x > 0.f ? x : 0.2f * x; }

__device__ __forceinline__ u16 f2b(float f) {
  union { float f; unsigned u; } v; v.f = f;
  unsigned r = v.u + 0x7FFF + ((v.u >> 16) & 1);
  return (u16)(r >> 16);
}
__device__ __forceinline__ float b2f(u16 u) {
  union { unsigned u; float f; } v; v.u = ((unsigned)u) << 16; return v.f;
}

// ---------------- fused conversions + degree count ----------------
__global__ __launch_bounds__(256) void cvtdeg_k(const float* __restrict__ x, u16* __restrict__ xb,
                                                int nx8,
                                                const float* __restrict__ pw,
                                                const float* __restrict__ w0,
                                                const float* __restrict__ w1,
                                                const float* __restrict__ w2,
                                                u16* __restrict__ dp, u16* __restrict__ d0,
                                                u16* __restrict__ d1, u16* __restrict__ d2,
                                                const int* __restrict__ edst,
                                                int E, int n, int* __restrict__ deg) {
  int i = blockIdx.x * 256 + threadIdx.x;
  if (i < nx8) {
    int j = i * 8;
    float4 a = *reinterpret_cast<const float4*>(&x[j]);
    float4 b = *reinterpret_cast<const float4*>(&x[j + 4]);
    u16x4 o0, o1;
    o0.x = f2b(a.x); o0.y = f2b(a.y); o0.z = f2b(a.z); o0.w = f2b(a.w);
    o1.x = f2b(b.x); o1.y = f2b(b.y); o1.z = f2b(b.z); o1.w = f2b(b.w);
    *reinterpret_cast<u16x4*>(&xb[j]) = o0;
    *reinterpret_cast<u16x4*>(&xb[j + 4]) = o1;
  } else if (i < nx8 + 155648) {
    int j = i - nx8;
    if (j < 8192) dp[j] = f2b(pw[j]);
    else if (j < 24576) d0[j - 8192] = f2b(w0[j - 8192]);
    else if (j < 90112) d1[j - 24576] = f2b(w1[j - 24576]);
    else d2[j - 90112] = f2b(w2[j - 90112]);
  } else {
    int j = i - (nx8 + 155648);
    if (j < E) atomicAdd(&deg[edst[j]], 1);
    else if (j < E + n) atomicAdd(&deg[j - E], 1);  // self loop
  }
}

__global__ __launch_bounds__(256) void block_sum_k(const int* __restrict__ deg,
                                                   int* __restrict__ bsum, int n) {
  int i = blockIdx.x * 256 + threadIdx.x;
  int v = (i < n) ? deg[i] : 0;
#pragma unroll
  for (int off = 1; off < 64; off <<= 1) v += __shfl_xor(v, off);
  __shared__ int ws[4];
  if ((threadIdx.x & 63) == 0) ws[threadIdx.x >> 6] = v;
  __syncthreads();
  if (threadIdx.x == 0) bsum[blockIdx.x] = ws[0] + ws[1] + ws[2] + ws[3];
}

__global__ void scan_bsum_k(int* __restrict__ bsum, int nb) {
  __shared__ int s[1024];
  int tid = threadIdx.x;
  int v = (tid < nb) ? bsum[tid] : 0;
  s[tid] = v;
  __syncthreads();
  for (int off = 1; off < 1024; off <<= 1) {
    int t = (tid >= off) ? s[tid - off] : 0;
    __syncthreads();
    s[tid] += t;
    __syncthreads();
  }
  if (tid < nb) bsum[tid] = s[tid] - v;  // exclusive
}

__global__ __launch_bounds__(256) void block_scan_k(const int* __restrict__ deg,
                                                    const int* __restrict__ bsum,
                                                    int* __restrict__ rowptr,
                                                    int* __restrict__ cursor, int n) {
  int i = blockIdx.x * 256 + threadIdx.x;
  int lane = threadIdx.x & 63, w = threadIdx.x >> 6;
  int v = (i < n) ? deg[i] : 0;
  int x = v;
#pragma unroll
  for (int off = 1; off < 64; off <<= 1) {
    int t = __shfl_up(x, off);
    if (lane >= off) x += t;
  }
  __shared__ int ws[4];
  if (lane == 63) ws[w] = x;
  __syncthreads();
  int add = bsum[blockIdx.x];
  for (int j = 0; j < w; ++j) add += ws[j];
  int excl = x - v + add;
  if (i < n) {
    cursor[i] = excl;
    rowptr[i + 1] = excl + v;
  }
  if (i == 0) rowptr[0] = 0;
}

__global__ void scatter_k(const int* __restrict__ src, const int* __restrict__ dst,
                          int E, int n, int* __restrict__ cursor,
                          int* __restrict__ col, int* __restrict__ dst2) {
  int e = blockIdx.x * blockDim.x + threadIdx.x;
  if (e < E) {
    int d = dst[e];
    int pos = atomicAdd(&cursor[d], 1);
    col[pos] = src[e];
    dst2[pos] = d;
  } else if (e < E + n) {
    int d = e - E;
    int pos = atomicAdd(&cursor[d], 1);
    col[pos] = d;  // self loop
    dst2[pos] = d;
  }
}

// ---------------- bf16 MFMA GEMM, 128x256 tile, fused attn scores (+optional fused proj) ----------------
// 512 threads, 8 waves (wrow=w>>2, wcol=w&3). head = wcol.
// PROJ=1: A = xb [n,128] bf16 (SEPARATE buffer from Cb! pitch differs); Asb computed in-block.
template <int PROJ>
__global__ __launch_bounds__(512) void gemm2_k(const u16* __restrict__ A, int lda,
                                               const u16* __restrict__ W,
                                               const u16* __restrict__ pw,
                                               const float* __restrict__ pb,
                                               u16* __restrict__ Cb,
                                               int n, int K,
                                               const float* __restrict__ a_sv,
                                               const float* __restrict__ a_dv,
                                               float* __restrict__ asrcN,
                                               float* __restrict__ adstN) {
  __shared__ char Asb[128 * 128];  // 128 rows x 128B, XOR-swizzled
  __shared__ char Bsb[256 * 128];  // 256 rows x 128B
  __shared__ char Xsb[PROJ ? 128 * 272 : 16];  // xb tile, padded stride
  __shared__ char Psb[PROJ ? 64 * 272 : 16];   // proj weights
  const int t = threadIdx.x;
  const int lane = t & 63, w = t >> 6;
  const int wrow = w >> 2, wcol = w & 3;
  const int row0 = blockIdx.x * 128;

  if (PROJ) {
#pragma unroll
    for (int i = 0; i < 4; ++i) {  // xb tile: 128 rows x 256B = 2048 chunks
      int ci = i * 512 + t;
      int r = ci >> 4;
      int b = (ci & 15) << 4;
      int ar = row0 + r; ar = ar < n ? ar : n - 1;
      *reinterpret_cast<int4*>(Xsb + r * 272 + b) =
          *reinterpret_cast<const int4*>(&A[(size_t)ar * 128 + (b >> 1)]);
    }
#pragma unroll
    for (int i = 0; i < 2; ++i) {  // pw: 64 rows x 256B = 1024 chunks
      int ci = i * 512 + t;
      int r = ci >> 4;
      int b = (ci & 15) << 4;
      *reinterpret_cast<int4*>(Psb + r * 272 + b) =
          *reinterpret_cast<const int4*>(&pw[r * 128 + (b >> 1)]);
    }
    __syncthreads();
    // wave w computes proj rows w*16..w*16+15, cols 0..63
    f32x4 pacc[4];
#pragma unroll
    for (int nf = 0; nf < 4; ++nf) pacc[nf] = (f32x4){0.f, 0.f, 0.f, 0.f};
#pragma unroll
    for (int ks = 0; ks < 4; ++ks) {  // K=128
      short8 paf = *reinterpret_cast<const short8*>(
          Xsb + (w * 16 + (lane & 15)) * 272 + ks * 64 + (lane >> 4) * 16);
#pragma unroll
      for (int nf = 0; nf < 4; ++nf) {
        short8 pbf = *reinterpret_cast<const short8*>(
            Psb + (nf * 16 + (lane & 15)) * 272 + ks * 64 + (lane >> 4) * 16);
        pacc[nf] = __builtin_amdgcn_mfma_f32_16x16x32_bf16(paf, pbf, pacc[nf], 0, 0, 0);
      }
    }
    // bias+elu -> bf16 -> swizzled Asb (A-tile for the K=64 main loop)
#pragma unroll
    for (int nf = 0; nf < 4; ++nf) {
#pragma unroll
      for (int j = 0; j < 4; ++j) {
        int rl = w * 16 + (lane >> 4) * 4 + j;
        int cg = nf * 16 + (lane & 15);
        u16 bv = f2b(elu_f(pacc[nf][j] + pb[cg]));
        *reinterpret_cast<u16*>(Asb + rl * 128 + ((cg * 2) ^ ((rl & 7) << 4))) = bv;
      }
    }
    // ordered before ds_reads by the main loop's post-staging barrier
  }

  f32x4 acc[4][4];
#pragma unroll
  for (int m = 0; m < 4; ++m)
#pragma unroll
    for (int nf = 0; nf < 4; ++nf) acc[m][nf] = (f32x4){0.f, 0.f, 0.f, 0.f};

  for (int k0 = 0; k0 < K; k0 += 64) {
    if (!PROJ) {
#pragma unroll
      for (int i = 0; i < 2; ++i) {  // A: 1024 chunks
        int ci = i * 512 + t;
        int r = ci >> 3;
        int b = (ci & 7) << 4;
        int sw = b ^ ((r & 7) << 4);
        int ar = row0 + r; ar = ar < n ? ar : n - 1;
        int4 av = *reinterpret_cast<const int4*>(&A[(size_t)ar * lda + k0 + (b >> 1)]);
        *reinterpret_cast<int4*>(Asb + r * 128 + sw) = av;
      }
    }
#pragma unroll
    for (int i = 0; i < 4; ++i) {  // B: 2048 chunks (256 rows)
      int ci = i * 512 + t;
      int r = ci >> 3;
      int b = (ci & 7) << 4;
      int sw = b ^ ((r & 7) << 4);
      int4 wv = *reinterpret_cast<const int4*>(&W[(size_t)r * K + k0 + (b >> 1)]);
      *reinterpret_cast<int4*>(Bsb + r * 128 + sw) = wv;
    }
    __syncthreads();
#pragma unroll
    for (int ks = 0; ks < 2; ++ks) {
      short8 af[4], bf[4];
      int kb = ks * 64 + ((lane >> 4) << 4);
#pragma unroll
      for (int m = 0; m < 4; ++m) {
        int r = wrow * 64 + m * 16 + (lane & 15);
        af[m] = *reinterpret_cast<const short8*>(Asb + r * 128 + (kb ^ ((r & 7) << 4)));
      }
#pragma unroll
      for (int nf = 0; nf < 4; ++nf) {
        int r = wcol * 64 + nf * 16 + (lane & 15);
        bf[nf] = *reinterpret_cast<const short8*>(Bsb + r * 128 + (kb ^ ((r & 7) << 4)));
      }
#pragma unroll
      for (int m = 0; m < 4; ++m)
#pragma unroll
        for (int nf = 0; nf < 4; ++nf)
          acc[m][nf] = __builtin_amdgcn_mfma_f32_16x16x32_bf16(af[m], bf[nf], acc[m][nf], 0, 0, 0);
    }
    __syncthreads();
  }
  // C write
#pragma unroll
  for (int m = 0; m < 4; ++m) {
#pragma unroll
    for (int j = 0; j < 4; ++j) {
      int rg = row0 + wrow * 64 + m * 16 + (lane >> 4) * 4 + j;
      if (rg >= n) continue;
#pragma unroll
      for (int nf = 0; nf < 4; ++nf) {
        int cg = wcol * 64 + nf * 16 + (lane & 15);
        Cb[(size_t)rg * 256 + cg] = f2b(acc[m][nf][j]);
      }
    }
  }
  // fused attention scores: this wave's 64-col block = head wcol
  {
    int h = wcol;
    int ch = lane & 15;
    float as_c[4], ad_c[4];
#pragma unroll
    for (int nf = 0; nf < 4; ++nf) {
      as_c[nf] = a_sv[h * 64 + nf * 16 + ch];
      ad_c[nf] = a_dv[h * 64 + nf * 16 + ch];
    }
#pragma unroll
    for (int m = 0; m < 4; ++m) {
#pragma unroll
      for (int j = 0; j < 4; ++j) {
        float ps = 0.f, pd = 0.f;
#pragma unroll
        for (int nf = 0; nf < 4; ++nf) {
          float v = acc[m][nf][j];
          ps += v * as_c[nf];
          pd += v * ad_c[nf];
        }
#pragma unroll
        for (int off = 1; off < 16; off <<= 1) {
          ps += __shfl_xor(ps, off);
          pd += __shfl_xor(pd, off);
        }
        int rg = row0 + wrow * 64 + m * 16 + (lane >> 4) * 4 + j;
        if ((lane & 15) == 0 && rg < n) {
          asrcN[(size_t)rg * 4 + h] = ps;
          adstN[(size_t)rg * 4 + h] = pd;
        }
      }
    }
  }
}

// ---------------- edge-parallel softmax numerators, transposed: exT[h][e] ----------------
__global__ __launch_bounds__(256) void edge_ex2_k(const int* __restrict__ col,
                                                  const int* __restrict__ dst2,
                                                  const float* __restrict__ asrcN,
                                                  const float* __restrict__ adstN,
                                                  float* __restrict__ exT, int eep, int EE) {
  int e = blockIdx.x * 256 + threadIdx.x;
  if (e >= EE) return;
  int s = col[e], d = dst2[e];
  float4 as = *reinterpret_cast<const float4*>(&asrcN[(size_t)s * 4]);
  float4 ad = *reinterpret_cast<const float4*>(&adstN[(size_t)d * 4]);
  exT[e]            = __expf(lrelu_f(as.x + ad.x));  // softmax shift-invariant; |a| <~ 5
  exT[eep + e]      = __expf(lrelu_f(as.y + ad.y));
  exT[2 * eep + e]  = __expf(lrelu_f(as.z + ad.z));
  exT[3 * eep + e]  = __expf(lrelu_f(as.w + ad.w));
}

// ---------------- fused GAT aggregation + bias + LayerNorm + ELU (+value head in MODE1) ----------------
// MODE 0: LN(256) -> bf16 row at (u16*)out + node*256
// MODE 1: head-mean -> bias -> LN(64) -> ELU -> value head -> f32 out[node*4..]
template <int MODE>
__global__ __launch_bounds__(256) void gat_agg4_k(const u16* __restrict__ feat,
                                                  const float* __restrict__ exT, int eep,
                                                  const int* __restrict__ rowptr,
                                                  const int* __restrict__ col,
                                                  const float* __restrict__ bias,
                                                  const float* __restrict__ g,
                                                  const float* __restrict__ be,
                                                  const float* __restrict__ vw1,
                                                  const float* __restrict__ vb1,
                                                  const float* __restrict__ vw2,
                                                  const float* __restrict__ vb2,
                                                  void* __restrict__ out, int n) {
  int wave = threadIdx.x >> 6, lane = threadIdx.x & 63;
  int node = blockIdx.x * 4 + wave;
  if (node >= n) return;
  int h = lane >> 4;
  const float* exh = exT + (size_t)h * eep;
  int s0 = rowptr[node], s1 = rowptr[node + 1];
  float ax = 0.f, ay = 0.f, az = 0.f, aw = 0.f, den = 0.f;
  int e = s0;
  for (; e + 8 <= s1; e += 8) {
    int p0 = col[e + 0], p1 = col[e + 1], p2 = col[e + 2], p3 = col[e + 3];
    int q0 = col[e + 4], q1 = col[e + 5], q2 = col[e + 6], q3 = col[e + 7];
    float u0 = exh[e + 0], u1 = exh[e + 1], u2 = exh[e + 2], u3 = exh[e + 3];
    float v0 = exh[e + 4], v1 = exh[e + 5], v2 = exh[e + 6], v3 = exh[e + 7];
    u16x4 fp0 = *reinterpret_cast<const u16x4*>(&feat[(size_t)p0 * 256 + lane * 4]);
    u16x4 fp1 = *reinterpret_cast<const u16x4*>(&feat[(size_t)p1 * 256 + lane * 4]);
    u16x4 fp2 = *reinterpret_cast<const u16x4*>(&feat[(size_t)p2 * 256 + lane * 4]);
    u16x4 fp3 = *reinterpret_cast<const u16x4*>(&feat[(size_t)p3 * 256 + lane * 4]);
    u16x4 fq0 = *reinterpret_cast<const u16x4*>(&feat[(size_t)q0 * 256 + lane * 4]);
    u16x4 fq1 = *reinterpret_cast<const u16x4*>(&feat[(size_t)q1 * 256 + lane * 4]);
    u16x4 fq2 = *reinterpret_cast<const u16x4*>(&feat[(size_t)q2 * 256 + lane * 4]);
    u16x4 fq3 = *reinterpret_cast<const u16x4*>(&feat[(size_t)q3 * 256 + lane * 4]);
    den += ((u0 + u1) + (u2 + u3)) + ((v0 + v1) + (v2 + v3));
    ax += u0 * b2f(fp0.x) + u1 * b2f(fp1.x) + u2 * b2f(fp2.x) + u3 * b2f(fp3.x);
    ay += u0 * b2f(fp0.y) + u1 * b2f(fp1.y) + u2 * b2f(fp2.y) + u3 * b2f(fp3.y);
    az += u0 * b2f(fp0.z) + u1 * b2f(fp1.z) + u2 * b2f(fp2.z) + u3 * b2f(fp3.z);
    aw += u0 * b2f(fp0.w) + u1 * b2f(fp1.w) + u2 * b2f(fp2.w) + u3 * b2f(fp3.w);
    ax += v0 * b2f(fq0.x) + v1 * b2f(fq1.x) + v2 * b2f(fq2.x) + v3 * b2f(fq3.x);
    ay += v0 * b2f(fq0.y) + v1 * b2f(fq1.y) + v2 * b2f(fq2.y) + v3 * b2f(fq3.y);
    az += v0 * b2f(fq0.z) + v1 * b2f(fq1.z) + v2 * b2f(fq2.z) + v3 * b2f(fq3.z);
    aw += v0 * b2f(fq0.w) + v1 * b2f(fq1.w) + v2 * b2f(fq2.w) + v3 * b2f(fq3.w);
  }
  for (; e + 4 <= s1; e += 4) {
    int p0 = col[e + 0], p1 = col[e + 1], p2 = col[e + 2], p3 = col[e + 3];
    float u0 = exh[e + 0], u1 = exh[e + 1], u2 = exh[e + 2], u3 = exh[e + 3];
    u16x4 fp0 = *reinterpret_cast<const u16x4*>(&feat[(size_t)p0 * 256 + lane * 4]);
    u16x4 fp1 = *reinterpret_cast<const u16x4*>(&feat[(size_t)p1 * 256 + lane * 4]);
    u16x4 fp2 = *reinterpret_cast<const u16x4*>(&feat[(size_t)p2 * 256 + lane * 4]);
    u16x4 fp3 = *reinterpret_cast<const u16x4*>(&feat[(size_t)p3 * 256 + lane * 4]);
    den += (u0 + u1) + (u2 + u3);
    ax += u0 * b2f(fp0.x) + u1 * b2f(fp1.x) + u2 * b2f(fp2.x) + u3 * b2f(fp3.x);
    ay += u0 * b2f(fp0.y) + u1 * b2f(fp1.y) + u2 * b2f(fp2.y) + u3 * b2f(fp3.y);
    az += u0 * b2f(fp0.z) + u1 * b2f(fp1.z) + u2 * b2f(fp2.z) + u3 * b2f(fp3.z);
    aw += u0 * b2f(fp0.w) + u1 * b2f(fp1.w) + u2 * b2f(fp2.w) + u3 * b2f(fp3.w);
  }
  for (; e < s1; ++e) {
    int s = col[e];
    float xv = exh[e];
    den += xv;
    u16x4 f = *reinterpret_cast<const u16x4*>(&feat[(size_t)s * 256 + lane * 4]);
    ax += xv * b2f(f.x); ay += xv * b2f(f.y); az += xv * b2f(f.z); aw += xv * b2f(f.w);
  }
  float inv = 1.f / den;  // self-loop guarantees den > 0
  ax *= inv; ay *= inv; az *= inv; aw *= inv;

  if (MODE == 0) {
    float4 b4 = *reinterpret_cast<const float4*>(&bias[lane * 4]);
    float vx = ax + b4.x, vy = ay + b4.y, vz = az + b4.z, vw = aw + b4.w;
    float s = vx + vy + vz + vw;
#pragma unroll
    for (int off = 1; off < 64; off <<= 1) s += __shfl_xor(s, off);
    float mu = s * (1.f / 256.f);
    float dx = vx - mu, dy = vy - mu, dz = vz - mu, dw = vw - mu;
    float q = dx * dx + dy * dy + dz * dz + dw * dw;
#pragma unroll
    for (int off = 1; off < 64; off <<= 1) q += __shfl_xor(q, off);
    float inv2 = rsqrtf(q * (1.f / 256.f) + 1e-5f);
    float4 gg = *reinterpret_cast<const float4*>(&g[lane * 4]);
    float4 bb = *reinterpret_cast<const float4*>(&be[lane * 4]);
    u16x4 o;
    o.x = f2b(elu_f(dx * inv2 * gg.x + bb.x));
    o.y = f2b(elu_f(dy * inv2 * gg.y + bb.y));
    o.z = f2b(elu_f(dz * inv2 * gg.z + bb.z));
    o.w = f2b(elu_f(dw * inv2 * gg.w + bb.w));
    u16* rowb = (u16*)out + (size_t)node * 256;
    *reinterpret_cast<u16x4*>(&rowb[lane * 4]) = o;
  } else {
    // head-mean over lane bits 4,5
    ax += __shfl_xor(ax, 16); ax += __shfl_xor(ax, 32);
    ay += __shfl_xor(ay, 16); ay += __shfl_xor(ay, 32);
    az += __shfl_xor(az, 16); az += __shfl_xor(az, 32);
    aw += __shfl_xor(aw, 16); aw += __shfl_xor(aw, 32);
    int qd = lane & 15;
    float4 b4 = *reinterpret_cast<const float4*>(&bias[qd * 4]);
    float vx = 0.25f * ax + b4.x, vy = 0.25f * ay + b4.y;
    float vz = 0.25f * az + b4.z, vw = 0.25f * aw + b4.w;
    // LN over 64 cols (each col replicated 4x -> /256)
    float s = vx + vy + vz + vw;
#pragma unroll
    for (int off = 1; off < 64; off <<= 1) s += __shfl_xor(s, off);
    float mu = s * (1.f / 256.f);
    float dx = vx - mu, dy = vy - mu, dz = vz - mu, dw = vw - mu;
    float q = dx * dx + dy * dy + dz * dz + dw * dw;
#pragma unroll
    for (int off = 1; off < 64; off <<= 1) q += __shfl_xor(q, off);
    float inv2 = rsqrtf(q * (1.f / 256.f) + 1e-5f);
    float4 gg = *reinterpret_cast<const float4*>(&g[qd * 4]);
    float4 bb = *reinterpret_cast<const float4*>(&be[qd * 4]);
    float h0 = elu_f(dx * inv2 * gg.x + bb.x);
    float h1 = elu_f(dy * inv2 * gg.y + bb.y);
    float h2 = elu_f(dz * inv2 * gg.z + bb.z);
    float h3 = elu_f(dw * inv2 * gg.w + bb.w);
    // value head: replica r = lane>>4 covers vw1 rows r*8..r*8+7
    int r = (lane >> 4) & 3;
    float pj[8];
#pragma unroll
    for (int jj = 0; jj < 8; ++jj) {
      int j = r * 8 + jj;
      float4 wv = *reinterpret_cast<const float4*>(&vw1[(size_t)j * 64 + qd * 4]);
      pj[jj] = h0 * wv.x + h1 * wv.y + h2 * wv.z + h3 * wv.w;
    }
#pragma unroll
    for (int off = 1; off < 16; off <<= 1) {
#pragma unroll
      for (int jj = 0; jj < 8; ++jj) pj[jj] += __shfl_xor(pj[jj], off);
    }
    float4 vb1a = *reinterpret_cast<const float4*>(&vb1[r * 8]);
    float4 vb1b = *reinterpret_cast<const float4*>(&vb1[r * 8 + 4]);
    float vj0 = elu_f(pj[0] + vb1a.x), vj1 = elu_f(pj[1] + vb1a.y);
    float vj2 = elu_f(pj[2] + vb1a.z), vj3 = elu_f(pj[3] + vb1a.w);
    float vj4 = elu_f(pj[4] + vb1b.x), vj5 = elu_f(pj[5] + vb1b.y);
    float vj6 = elu_f(pj[6] + vb1b.z), vj7 = elu_f(pj[7] + vb1b.w);
    float qo[4];
#pragma unroll
    for (int o = 0; o < 4; ++o) {
      float4 w2a = *reinterpret_cast<const float4*>(&vw2[o * 32 + r * 8]);
      float4 w2b = *reinterpret_cast<const float4*>(&vw2[o * 32 + r * 8 + 4]);
      qo[o] = vj0 * w2a.x + vj1 * w2a.y + vj2 * w2a.z + vj3 * w2a.w +
              vj4 * w2b.x + vj5 * w2b.y + vj6 * w2b.z + vj7 * w2b.w;
    }
#pragma unroll
    for (int o = 0; o < 4; ++o) {
      qo[o] += __shfl_xor(qo[o], 16);
      qo[o] += __shfl_xor(qo[o], 32);
    }
    if (lane == 0) {
      float4 vb2v = *reinterpret_cast<const float4*>(&vb2[0]);
      float4 o4;
      o4.x = qo[0] + vb2v.x; o4.y = qo[1] + vb2v.y;
      o4.z = qo[2] + vb2v.z; o4.w = qo[3] + vb2v.w;
      *reinterpret_cast<float4*>(&((float*)out)[(size_t)node * 4]) = o4;
    }
  }
}

extern "C" void kernel_launch(void* const* d_in, const int* in_sizes, int n_in,
                              void* d_out, int out_size, void* d_ws, size_t ws_size,
                              hipStream_t stream) {
  const float* x      = (const float*)d_in[0];
  const int*   esrc   = (const int*)d_in[1];
  const int*   edst   = (const int*)d_in[2];
  const float* proj_w = (const float*)d_in[3];
  const float* proj_b = (const float*)d_in[4];
  const float* w[3]   = {(const float*)d_in[5],  (const float*)d_in[11], (const float*)d_in[17]};
  const float* a_s[3] = {(const float*)d_in[6],  (const float*)d_in[12], (const float*)d_in[18]};
  const float* a_d[3] = {(const float*)d_in[7],  (const float*)d_in[13], (const float*)d_in[19]};
  const float* bb[3]  = {(const float*)d_in[8],  (const float*)d_in[14], (const float*)d_in[20]};
  const float* gg[3]  = {(const float*)d_in[9],  (const float*)d_in[15], (const float*)d_in[21]};
  const float* be[3]  = {(const float*)d_in[10], (const float*)d_in[16], (const float*)d_in[22]};
  const float* vw1 = (const float*)d_in[23];
  const float* vb1 = (const float*)d_in[24];
  const float* vw2 = (const float*)d_in[25];
  const float* vb2 = (const float*)d_in[26];
  float* outp = (float*)d_out;

  const int n = in_sizes[0] / 128;
  const int E = in_sizes[1];
  const int EE = E + n;
  const int eep = (EE + 255) & ~255;
  const int nbl = (n + 255) / 256;

  // ---- workspace layout ----
  char* p = (char*)d_ws;
  auto alloc = [&](size_t bytes) { char* r = p; p += (bytes + 255) & ~(size_t)255; return r; };
  u16*   hA    = (u16*)alloc((size_t)n * 512);     // packed bf16 [n,256] layer input
  u16*   featB = (u16*)alloc((size_t)n * 512);     // bf16 [n,256] gemm output
  u16*   xb    = (u16*)alloc((size_t)n * 256);     // bf16 [n,128] input x (own buffer — no aliasing!)
  float* exT   = (float*)alloc((size_t)eep * 16);  // transposed numerators [4][eep]
  float* asrcN = (float*)alloc((size_t)n * 16);
  float* adstN = (float*)alloc((size_t)n * 16);
  u16* wbp = (u16*)alloc(64 * 128 * 2);
  u16* wb[3];
  wb[0] = (u16*)alloc(256 * 64 * 2);
  wb[1] = (u16*)alloc(256 * 256 * 2);
  wb[2] = (u16*)alloc(256 * 256 * 2);
  int* deg    = (int*)alloc((size_t)n * 4);
  int* rowptr = (int*)alloc((size_t)(n + 1) * 4);
  int* cursor = (int*)alloc((size_t)n * 4);
  int* col    = (int*)alloc((size_t)EE * 4);
  int* dst2   = (int*)alloc((size_t)EE * 4);
  int* bsum   = (int*)alloc((size_t)nbl * 4);

  // ---- CSR build + conversions ----
  hipMemsetAsync(deg, 0, (size_t)n * sizeof(int), stream);
  const int nx8 = n * 16;
  cvtdeg_k<<<(nx8 + 155648 + EE + 255) / 256, 256, 0, stream>>>(
      x, xb, nx8, proj_w, w[0], w[1], w[2], wbp, wb[0], wb[1], wb[2], edst, E, n, deg);
  block_sum_k<<<nbl, 256, 0, stream>>>(deg, bsum, n);
  scan_bsum_k<<<1, 1024, 0, stream>>>(bsum, nbl);
  block_scan_k<<<nbl, 256, 0, stream>>>(deg, bsum, rowptr, cursor, n);
  scatter_k<<<(EE + 255) / 256, 256, 0, stream>>>(esrc, edst, E, n, cursor, col, dst2);

  const int nb4 = (n + 3) / 4;
  const int nbg = (n + 127) / 128;
  dim3 blk(256);

  const int Kin[3] = {64, 256, 256};
  for (int i = 0; i < 3; ++i) {
    if (i == 0) {
      // fused proj + layer-0 GEMM: reads xb, writes featB (distinct buffers)
      gemm2_k<1><<<nbg, 512, 0, stream>>>(xb, 128, wb[0], wbp, proj_b, featB,
                                          n, 64, a_s[0], a_d[0], asrcN, adstN);
    } else {
      gemm2_k<0><<<nbg, 512, 0, stream>>>(hA, 256, wb[i], nullptr, nullptr, featB,
                                          n, Kin[i], a_s[i], a_d[i], asrcN, adstN);
    }
    edge_ex2_k<<<(EE + 255) / 256, 256, 0, stream>>>(col, dst2, asrcN, adstN, exT, eep, EE);
    if (i < 2) {
      gat_agg4_k<0><<<nb4, blk, 0, stream>>>(featB, exT, eep, rowptr, col, bb[i], gg[i], be[i],
                                             nullptr, nullptr, nullptr, nullptr, (void*)hA, n);
    } else {
      gat_agg4_k<1><<<nb4, blk, 0, stream>>>(featB, exT, eep, rowptr, col, bb[i], gg[i], be[i],
                                             vw1, vb1, vw2, vb2, (void*)outp, n);
    }
  }
}